// Round 1
// baseline (244.218 us; speedup 1.0000x reference)
//
#include <hip/hip_runtime.h>
#include <hip/hip_bf16.h>

#define BSZ 4
#define S1v 2048
#define S2v 2048
#define DM 512
#define NH 8
#define HD 64
#define SCALE 0.044194173824159216f
#define L2E 1.4426950408889634f
#define SC_L2E (0.044194173824159216f * 1.4426950408889634f)
#define CBIAS 0.0028152f   /* log2(1+2^-9): centers truncating bf16 pack */
#define NEGB (-1e30f)

typedef __bf16 bf16x8 __attribute__((ext_vector_type(8)));
typedef float f32x4 __attribute__((ext_vector_type(4)));

__device__ __forceinline__ unsigned short f2bf(float f) {
  union { float f; unsigned u; } v; v.f = f;
  unsigned r = v.u + 0x7FFFu + ((v.u >> 16) & 1u);
  return (unsigned short)(r >> 16);
}
__device__ __forceinline__ unsigned asu(float f) {
  union { float f; unsigned u; } v; v.f = f; return v.u;
}

// ---------------- weight transpose + cast: Wt[n][k] = bf16(W[k][n]) ------------
__global__ __launch_bounds__(256)
void wtrans(const float* __restrict__ W, unsigned short* __restrict__ Wt) {
  __shared__ float tile[32][33];
  const int tx = threadIdx.x, ty = threadIdx.y;     // block (32,8)
  const int n0 = blockIdx.x * 32, k0 = blockIdx.y * 32;
#pragma unroll
  for (int i = 0; i < 32; i += 8)
    tile[ty + i][tx] = W[(size_t)(k0 + ty + i) * DM + n0 + tx];
  __syncthreads();
#pragma unroll
  for (int i = 0; i < 32; i += 8)
    Wt[(size_t)(n0 + ty + i) * DM + k0 + tx] = f2bf(tile[tx][ty + i]);
}

// ---------------- projection GEMM: Y(bf16)[8192x512] = X(f32) @ W + bias -------
// 512 threads (8 waves, 2/SIMD) + register ping-pong prefetch of next K-tile:
// global-load latency hides under the MFMA phase instead of stalling the barrier.
__global__ __launch_bounds__(512, 2)
void proj_gemm(const float* __restrict__ X, const unsigned short* __restrict__ Wt,
               const float* __restrict__ bias, unsigned short* __restrict__ Y) {
  __shared__ unsigned short Xs[128][72];
  __shared__ unsigned short Ws[128][72];
  const int tid = threadIdx.x;
  const int wv = tid >> 6, lane = tid & 63;
  const int ln = lane & 15, qd = lane >> 4, q8 = qd * 8;
  const int wm = (wv >> 2) * 64, wn = (wv & 3) * 32;
  const int m0 = blockIdx.x * 128, n0 = blockIdx.y * 128;
  const int rX = tid >> 4, cX = (tid & 15) * 4;     // X stage: 4 x float4 / thread
  const int rW = tid >> 3, cW = (tid & 7) * 8;      // W stage: 2 x uint4  / thread
  const float* xbase = X + (size_t)(m0 + rX) * DM + cX;
  const unsigned short* wbase = Wt + (size_t)(n0 + rW) * DM + cW;
  f32x4 acc[4][2] = {};
  float4 px[4]; uint4 pw[2];
#pragma unroll
  for (int i = 0; i < 4; ++i) px[i] = *(const float4*)(xbase + (size_t)(i * 32) * DM);
#pragma unroll
  for (int i = 0; i < 2; ++i) pw[i] = *(const uint4*)(wbase + (size_t)(i * 64) * DM);
  for (int k0 = 0; k0 < DM; k0 += 64) {
    __syncthreads();
#pragma unroll
    for (int i = 0; i < 4; ++i) {                   // f32 -> bf16 at write time
      ushort4 bv;
      bv.x = f2bf(px[i].x); bv.y = f2bf(px[i].y);
      bv.z = f2bf(px[i].z); bv.w = f2bf(px[i].w);
      *(ushort4*)&Xs[rX + i * 32][cX] = bv;
    }
#pragma unroll
    for (int i = 0; i < 2; ++i) *(uint4*)&Ws[rW + i * 64][cW] = pw[i];
    __syncthreads();
    const int kn = (k0 + 64) & (DM - 1);            // wrap: last-iter loads unused
#pragma unroll
    for (int i = 0; i < 4; ++i) px[i] = *(const float4*)(xbase + (size_t)(i * 32) * DM + kn);
#pragma unroll
    for (int i = 0; i < 2; ++i) pw[i] = *(const uint4*)(wbase + (size_t)(i * 64) * DM + kn);
#pragma unroll
    for (int kk = 0; kk < 2; ++kk) {
      bf16x8 aF[4], bF[2];
#pragma unroll
      for (int i = 0; i < 4; ++i)
        aF[i] = *(const bf16x8*)&Xs[wm + 16 * i + ln][kk * 32 + q8];
#pragma unroll
      for (int j = 0; j < 2; ++j)
        bF[j] = *(const bf16x8*)&Ws[wn + 16 * j + ln][kk * 32 + q8];
      __builtin_amdgcn_s_setprio(1);
#pragma unroll
      for (int i = 0; i < 4; ++i)
#pragma unroll
        for (int j = 0; j < 2; ++j)
          acc[i][j] = __builtin_amdgcn_mfma_f32_16x16x32_bf16(aF[i], bF[j], acc[i][j], 0, 0, 0);
      __builtin_amdgcn_s_setprio(0);
    }
  }
#pragma unroll
  for (int i = 0; i < 4; ++i)
#pragma unroll
    for (int j = 0; j < 2; ++j) {
      const int n = n0 + wn + 16 * j + ln;
      const float bb = bias[n];
#pragma unroll
      for (int r = 0; r < 4; ++r) {
        const int m = m0 + wm + 16 * i + qd * 4 + r;
        Y[(size_t)m * DM + n] = f2bf(acc[i][j][r] + bb);
      }
    }
}

// ---------------- K^T builder with k-permutation baked in ----------------------
// Kt[(bh*64+d)][s_blk*128 + c'] = K[b][s_blk*128 + sigma(c')][h*64+d]
// sigma(c') = 16*(c'&7) + (c'>>3); matches the P-store layout in flash_attn.
__global__ __launch_bounds__(256)
void ktrans(const unsigned short* __restrict__ K, unsigned short* __restrict__ Kt) {
  __shared__ unsigned short T[128][72];
  const int tid = threadIdx.x;
  const int bh = blockIdx.y, b = bh >> 3, h = bh & 7;
  const int s0 = blockIdx.x * 128;
#pragma unroll
  for (int i = 0; i < 4; ++i) {                     // load tile [128 s][64 d]
    int cid = tid + i * 256;
    int r = cid >> 3, ch = (cid & 7) * 8;
    *(uint4*)&T[r][ch] =
        *(const uint4*)(K + (size_t)(b * S2v + s0 + r) * DM + h * HD + ch);
  }
  __syncthreads();
#pragma unroll
  for (int i = 0; i < 4; ++i) {                     // write [64 d][128 c']
    int cid = tid + i * 256;
    int d = cid >> 4, a = cid & 15;                 // c' = a*8 + k
    ushort4 v0, v1;
    v0.x = T[16 * 0 + a][d]; v0.y = T[16 * 1 + a][d];
    v0.z = T[16 * 2 + a][d]; v0.w = T[16 * 3 + a][d];
    v1.x = T[16 * 4 + a][d]; v1.y = T[16 * 5 + a][d];
    v1.z = T[16 * 6 + a][d]; v1.w = T[16 * 7 + a][d];
    unsigned short* o = Kt + ((size_t)(bh * HD + d)) * (size_t)S2v + s0 + a * 8;
    *(ushort4*)o = v0;
    *(ushort4*)(o + 4) = v1;
  }
}

// ---------------- flash attention (V = K), masked, static softmax --------------
// grid (S1/128, BSZ*NH), block 256: 4 waves x 32 Q-rows (2 subtiles of 16).
// This round: (1) register ping-pong prefetch of next K/Vt/m2 tile, issued after
// the staging barrier so its latency hides under QK+softmax+PV; (2) bijective
// XCD swizzle (512 blocks, 64-chunk/XCD -> 4 bh-panels/XCD, ~3MB < L2);
// (3) s_setprio(1) around the MFMA clusters (T5).
__global__ __launch_bounds__(256, 2)
void flash_attn(const unsigned short* __restrict__ Qb, const unsigned short* __restrict__ Kb,
                const unsigned short* __restrict__ Kt, const int* __restrict__ m1,
                const int* __restrict__ m2, float* __restrict__ attn) {
  __shared__ unsigned short Ks[128][72];
  __shared__ unsigned short Vts[64][136];
  __shared__ unsigned short Ps[4][32][136];
  __shared__ int m2s[128];

  const int tid = threadIdx.x;
  const int wv = tid >> 6, lane = tid & 63;
  const int ln = lane & 15, qd = lane >> 4, q8 = qd * 8;
  // XCD swizzle: lin = dispatch order; chunk of 64 consecutive logical blocks per XCD
  const int lin = blockIdx.x + (blockIdx.y << 4);       // gridDim.x == 16
  const int lid = ((lin & 7) << 6) | (lin >> 3);        // bijective (512 % 8 == 0)
  const int bh = lid >> 4;
  const int b = bh >> 3, h = bh & 7;
  const int q0 = (lid & 15) << 7;

  // staging coordinates (per-thread, constant across iterations)
  const int rK = tid >> 3, cK = (tid & 7) * 8;          // K tile: 4 x uint4 / thread
  const int rV = tid >> 4, cV = (tid & 15) * 8;         // Vt tile: 4 x uint4 / thread
  const unsigned short* kbase = Kb + ((size_t)(b * S2v) + rK) * DM + h * HD + cK;
  const unsigned short* vbase = Kt + ((size_t)(bh * HD + rV)) * (size_t)S2v + cV;
  const int* m2base = m2 + b * S2v + (tid & 127);

  // Q fragments straight from global (one-time, L2-warm from proj_gemm)
  bf16x8 aQ[2][2];
#pragma unroll
  for (int t = 0; t < 2; ++t) {
    const size_t rbase =
        ((size_t)(b * S1v + q0 + wv * 32 + t * 16 + ln)) * DM + h * HD;
    aQ[t][0] = *(const bf16x8*)(Qb + rbase + q8);
    aQ[t][1] = *(const bf16x8*)(Qb + rbase + 32 + q8);
  }

  float acoef[2][4];                                // 0 if m1==0 (uniform row)
#pragma unroll
  for (int t = 0; t < 2; ++t)
#pragma unroll
    for (int r = 0; r < 4; ++r)
      acoef[t][r] = (m1[b * S1v + q0 + wv * 32 + t * 16 + qd * 4 + r] == 0) ? 0.f : 1.f;

  float lrow[2][4] = {};
  f32x4 O[2][4] = {};

  // prologue: prefetch tile 0 into registers
  uint4 pk[4], pv[4]; int pm = 0;
#pragma unroll
  for (int i = 0; i < 4; ++i)
    pk[i] = *(const uint4*)(kbase + (size_t)(i * 32) * DM);
#pragma unroll
  for (int i = 0; i < 4; ++i)
    pv[i] = *(const uint4*)(vbase + (size_t)(i * 16) * (size_t)S2v);
  if (tid < 128) pm = m2base[0];

  for (int s0 = 0; s0 < S2v; s0 += 128) {
    __syncthreads();
#pragma unroll
    for (int i = 0; i < 4; ++i) *(uint4*)&Ks[rK + i * 32][cK] = pk[i];
#pragma unroll
    for (int i = 0; i < 4; ++i) *(uint4*)&Vts[rV + i * 16][cV] = pv[i];
    if (tid < 128) m2s[tid] = pm;
    __syncthreads();

    // prefetch NEXT tile now; latency hides under QK + softmax + PV.
    // (wraps to tile 0 on the last iteration; loads valid, values unused)
    const int sn = (s0 + 128) & (S2v - 1);
    uint4 nk[4], nv[4]; int nm = 0;
#pragma unroll
    for (int i = 0; i < 4; ++i)
      nk[i] = *(const uint4*)(kbase + ((size_t)sn + (size_t)(i * 32)) * DM);
#pragma unroll
    for (int i = 0; i < 4; ++i)
      nv[i] = *(const uint4*)(vbase + sn + (size_t)(i * 16) * (size_t)S2v);
    if (tid < 128) nm = m2base[sn];

    // S = Q K^T : two 16-row subtiles share the K fragments
    f32x4 sc[2][8];
    __builtin_amdgcn_s_setprio(1);
#pragma unroll
    for (int j = 0; j < 8; ++j) {
      const bf16x8 b0 = *(const bf16x8*)&Ks[16 * j + ln][q8];
      const bf16x8 b1 = *(const bf16x8*)&Ks[16 * j + ln][32 + q8];
#pragma unroll
      for (int t = 0; t < 2; ++t) {
        f32x4 z = {};
        z = __builtin_amdgcn_mfma_f32_16x16x32_bf16(aQ[t][0], b0, z, 0, 0, 0);
        sc[t][j] = __builtin_amdgcn_mfma_f32_16x16x32_bf16(aQ[t][1], b1, z, 0, 0, 0);
      }
    }
    __builtin_amdgcn_s_setprio(0);

    float moff[8];
#pragma unroll
    for (int j = 0; j < 8; ++j)
      moff[j] = (m2s[16 * j + ln] != 0) ? 0.f : NEGB;

    // p = exp2( a * (sc*SC_L2E + moff) + CBIAS ); masked->0, uniform rows->2^CBIAS
#pragma unroll
    for (int t = 0; t < 2; ++t)
#pragma unroll
      for (int j = 0; j < 8; ++j)
#pragma unroll
        for (int r = 0; r < 4; ++r) {
          const float e = fmaf(acoef[t][r], fmaf(sc[t][j][r], SC_L2E, moff[j]), CBIAS);
          const float p = __builtin_amdgcn_exp2f(e);
          lrow[t][r] += p;
          sc[t][j][r] = p;
        }

    // pack: row q, cols c' = ln*8 .. ln*8+7  (one ds_write_b128 per (t,r))
#pragma unroll
    for (int t = 0; t < 2; ++t)
#pragma unroll
      for (int r = 0; r < 4; ++r) {
        uint4 dw;
        dw.x = __builtin_amdgcn_perm(asu(sc[t][1][r]), asu(sc[t][0][r]), 0x07060302u);
        dw.y = __builtin_amdgcn_perm(asu(sc[t][3][r]), asu(sc[t][2][r]), 0x07060302u);
        dw.z = __builtin_amdgcn_perm(asu(sc[t][5][r]), asu(sc[t][4][r]), 0x07060302u);
        dw.w = __builtin_amdgcn_perm(asu(sc[t][7][r]), asu(sc[t][6][r]), 0x07060302u);
        *(uint4*)&Ps[wv][t * 16 + qd * 4 + r][ln * 8] = dw;
      }
    // order + drain the P stores before the A-fragment reads (wave-private tile)
    __asm__ volatile("s_waitcnt lgkmcnt(0)" ::: "memory");

    // O += P V : subtiles share the V fragments
    __builtin_amdgcn_s_setprio(1);
#pragma unroll
    for (int kk = 0; kk < 4; ++kk) {
      const bf16x8 aP0 = *(const bf16x8*)&Ps[wv][ln][kk * 32 + q8];
      const bf16x8 aP1 = *(const bf16x8*)&Ps[wv][16 + ln][kk * 32 + q8];
#pragma unroll
      for (int jn = 0; jn < 4; ++jn) {
        const bf16x8 bV = *(const bf16x8*)&Vts[16 * jn + ln][kk * 32 + q8];
        O[0][jn] = __builtin_amdgcn_mfma_f32_16x16x32_bf16(aP0, bV, O[0][jn], 0, 0, 0);
        O[1][jn] = __builtin_amdgcn_mfma_f32_16x16x32_bf16(aP1, bV, O[1][jn], 0, 0, 0);
      }
    }
    __builtin_amdgcn_s_setprio(0);

    // rotate prefetch registers
#pragma unroll
    for (int i = 0; i < 4; ++i) { pk[i] = nk[i]; pv[i] = nv[i]; }
    pm = nm;
  }

#pragma unroll
  for (int t = 0; t < 2; ++t)
#pragma unroll
    for (int r = 0; r < 4; ++r) {
      float l = lrow[t][r];
#pragma unroll
      for (int msk = 1; msk < 16; msk <<= 1) l += __shfl_xor(l, msk, 64);
      const float inv = l > 0.f ? 1.0f / l : 0.f;
      const int m = q0 + wv * 32 + t * 16 + qd * 4 + r;
#pragma unroll
      for (int jn = 0; jn < 4; ++jn)
        attn[((size_t)(b * S1v + m)) * DM + h * HD + 16 * jn + ln] = O[t][jn][r] * inv;
    }
}

// ---------------- fused LN2(attn + LN1(attn + modal1)) ------------------------
__global__ __launch_bounds__(128)
void ln_fused(const float* __restrict__ attn, const float* __restrict__ modal1,
              const float* __restrict__ g1, const float* __restrict__ b1,
              const float* __restrict__ g2, const float* __restrict__ b2,
              float* __restrict__ out) {
  __shared__ float red[4];
  const int row = blockIdx.x, t = threadIdx.x;
  const size_t base = (size_t)row * DM + t * 4;
  const float4 a = *(const float4*)(attn + base);
  const float4 mo = *(const float4*)(modal1 + base);
  float av[4] = { a.x, a.y, a.z, a.w };
  float x[4] = { a.x + mo.x, a.y + mo.y, a.z + mo.z, a.w + mo.w };
  float s = 0.f, q = 0.f;
#pragma unroll
  for (int i = 0; i < 4; ++i) { s += x[i]; q += x[i] * x[i]; }
#pragma unroll
  for (int m = 1; m < 64; m <<= 1) { s += __shfl_xor(s, m, 64); q += __shfl_xor(q, m, 64); }
  if ((t & 63) == 0) { red[t >> 6] = s; red[2 + (t >> 6)] = q; }
  __syncthreads();
  s = red[0] + red[1]; q = red[2] + red[3];
  const float mu = s * (1.0f / DM);
  const float rinv = rsqrtf(q * (1.0f / DM) - mu * mu + 1e-5f);
  const int c = t * 4;
  const float4 G1 = *(const float4*)(g1 + c), B1 = *(const float4*)(b1 + c);
  const float gg1[4] = { G1.x, G1.y, G1.z, G1.w }, bb1[4] = { B1.x, B1.y, B1.z, B1.w };
  float y[4];
  float s2 = 0.f, q2 = 0.f;
#pragma unroll
  for (int i = 0; i < 4; ++i) {
    y[i] = av[i] + (x[i] - mu) * rinv * gg1[i] + bb1[i];
    s2 += y[i]; q2 += y[i] * y[i];
  }
#pragma unroll
  for (int m = 1; m < 64; m <<= 1) { s2 += __shfl_xor(s2, m, 64); q2 += __shfl_xor(q2, m, 64); }
  __syncthreads();
  if ((t & 63) == 0) { red[t >> 6] = s2; red[2 + (t >> 6)] = q2; }
  __syncthreads();
  s2 = red[0] + red[1]; q2 = red[2] + red[3];
  const float mu2 = s2 * (1.0f / DM);
  const float rinv2 = rsqrtf(q2 * (1.0f / DM) - mu2 * mu2 + 1e-5f);
  const float4 G2 = *(const float4*)(g2 + c), B2 = *(const float4*)(b2 + c);
  float4 o;
  o.x = (y[0] - mu2) * rinv2 * G2.x + B2.x;
  o.y = (y[1] - mu2) * rinv2 * G2.y + B2.y;
  o.z = (y[2] - mu2) * rinv2 * G2.z + B2.z;
  o.w = (y[3] - mu2) * rinv2 * G2.w + B2.w;
  *(float4*)(out + base) = o;
}

extern "C" void kernel_launch(void* const* d_in, const int* in_sizes, int n_in,
                              void* d_out, int out_size, void* d_ws, size_t ws_size,
                              hipStream_t stream) {
  const float* modal1 = (const float*)d_in[0];
  const float* modal2 = (const float*)d_in[1];
  const int*   m1     = (const int*)d_in[2];
  const int*   m2     = (const int*)d_in[3];
  const float* Wq     = (const float*)d_in[4];
  const float* bq     = (const float*)d_in[5];
  const float* Wkv    = (const float*)d_in[6];
  const float* bkv    = (const float*)d_in[7];
  const float* g1     = (const float*)d_in[8];
  const float* b1     = (const float*)d_in[9];
  // d_in[10..13] = FFN weights -> output discarded by the reference; skipped.
  const float* g2     = (const float*)d_in[14];
  const float* b2     = (const float*)d_in[15];
  float* out = (float*)d_out;

  char* ws = (char*)d_ws;
  unsigned short* q_bf  = (unsigned short*)(ws);                 //  8 MB
  unsigned short* k_bf  = (unsigned short*)(ws + 8388608);       //  8 MB
  unsigned short* kt_bf = (unsigned short*)(ws + 16777216);      //  8 MB
  unsigned short* wqt   = (unsigned short*)(ws + 25165824);      // 512 KB
  unsigned short* wkt   = (unsigned short*)(ws + 25690112);      // 512 KB
  float*          attn  = (float*)(ws + 26214400);               // 16 MB

  dim3 tb(32, 8);
  wtrans<<<dim3(16, 16), tb, 0, stream>>>(Wq, wqt);
  wtrans<<<dim3(16, 16), tb, 0, stream>>>(Wkv, wkt);
  proj_gemm<<<dim3(64, 4), 512, 0, stream>>>(modal1, wqt, bq, q_bf);
  proj_gemm<<<dim3(64, 4), 512, 0, stream>>>(modal2, wkt, bkv, k_bf);
  ktrans<<<dim3(16, 32), 256, 0, stream>>>(k_bf, kt_bf);
  flash_attn<<<dim3(16, 32), 256, 0, stream>>>(q_bf, k_bf, kt_bf, m1, m2, attn);
  ln_fused<<<dim3(8192), 128, 0, stream>>>(attn, modal1, g1, b1, g2, b2, out);
}

// Round 2
// 224.249 us; speedup vs baseline: 1.0890x; 1.0890x over previous
//
#include <hip/hip_runtime.h>
#include <hip/hip_bf16.h>

#define BSZ 4
#define S1v 2048
#define S2v 2048
#define DM 512
#define NH 8
#define HD 64
#define SCALE 0.044194173824159216f
#define L2E 1.4426950408889634f
#define SC_L2E (0.044194173824159216f * 1.4426950408889634f)
#define CBIAS 0.0028152f   /* log2(1+2^-9): centers truncating bf16 pack */
#define NEGB (-1e30f)

typedef __bf16 bf16x8 __attribute__((ext_vector_type(8)));
typedef float f32x4 __attribute__((ext_vector_type(4)));

__device__ __forceinline__ unsigned short f2bf(float f) {
  union { float f; unsigned u; } v; v.f = f;
  unsigned r = v.u + 0x7FFFu + ((v.u >> 16) & 1u);
  return (unsigned short)(r >> 16);
}
__device__ __forceinline__ unsigned asu(float f) {
  union { float f; unsigned u; } v; v.f = f; return v.u;
}

// ---------------- weight transpose + cast: Wt[n][k] = bf16(W[k][n]) ------------
__global__ __launch_bounds__(256)
void wtrans(const float* __restrict__ W, unsigned short* __restrict__ Wt) {
  __shared__ float tile[32][33];
  const int tx = threadIdx.x, ty = threadIdx.y;     // block (32,8)
  const int n0 = blockIdx.x * 32, k0 = blockIdx.y * 32;
#pragma unroll
  for (int i = 0; i < 32; i += 8)
    tile[ty + i][tx] = W[(size_t)(k0 + ty + i) * DM + n0 + tx];
  __syncthreads();
#pragma unroll
  for (int i = 0; i < 32; i += 8)
    Wt[(size_t)(n0 + ty + i) * DM + k0 + tx] = f2bf(tile[tx][ty + i]);
}

// ---------------- projection GEMM: Y(bf16)[8192x512] = X(f32) @ W + bias -------
// 512 threads (8 waves, 2/SIMD) + single-set register prefetch of next K-tile.
__global__ __launch_bounds__(512, 2)
void proj_gemm(const float* __restrict__ X, const unsigned short* __restrict__ Wt,
               const float* __restrict__ bias, unsigned short* __restrict__ Y) {
  __shared__ unsigned short Xs[128][72];
  __shared__ unsigned short Ws[128][72];
  const int tid = threadIdx.x;
  const int wv = tid >> 6, lane = tid & 63;
  const int ln = lane & 15, qd = lane >> 4, q8 = qd * 8;
  const int wm = (wv >> 2) * 64, wn = (wv & 3) * 32;
  const int m0 = blockIdx.x * 128, n0 = blockIdx.y * 128;
  const int rX = tid >> 4, cX = (tid & 15) * 4;     // X stage: 4 x float4 / thread
  const int rW = tid >> 3, cW = (tid & 7) * 8;      // W stage: 2 x uint4  / thread
  const float* xbase = X + (size_t)(m0 + rX) * DM + cX;
  const unsigned short* wbase = Wt + (size_t)(n0 + rW) * DM + cW;
  f32x4 acc[4][2] = {};
  float4 px[4]; uint4 pw[2];
#pragma unroll
  for (int i = 0; i < 4; ++i) px[i] = *(const float4*)(xbase + (size_t)(i * 32) * DM);
#pragma unroll
  for (int i = 0; i < 2; ++i) pw[i] = *(const uint4*)(wbase + (size_t)(i * 64) * DM);
  for (int k0 = 0; k0 < DM; k0 += 64) {
    __syncthreads();
#pragma unroll
    for (int i = 0; i < 4; ++i) {                   // f32 -> bf16 at write time
      ushort4 bv;
      bv.x = f2bf(px[i].x); bv.y = f2bf(px[i].y);
      bv.z = f2bf(px[i].z); bv.w = f2bf(px[i].w);
      *(ushort4*)&Xs[rX + i * 32][cX] = bv;
    }
#pragma unroll
    for (int i = 0; i < 2; ++i) *(uint4*)&Ws[rW + i * 64][cW] = pw[i];
    __syncthreads();
    const int kn = (k0 + 64) & (DM - 1);            // wrap: last-iter loads unused
#pragma unroll
    for (int i = 0; i < 4; ++i) px[i] = *(const float4*)(xbase + (size_t)(i * 32) * DM + kn);
#pragma unroll
    for (int i = 0; i < 2; ++i) pw[i] = *(const uint4*)(wbase + (size_t)(i * 64) * DM + kn);
#pragma unroll
    for (int kk = 0; kk < 2; ++kk) {
      bf16x8 aF[4], bF[2];
#pragma unroll
      for (int i = 0; i < 4; ++i)
        aF[i] = *(const bf16x8*)&Xs[wm + 16 * i + ln][kk * 32 + q8];
#pragma unroll
      for (int j = 0; j < 2; ++j)
        bF[j] = *(const bf16x8*)&Ws[wn + 16 * j + ln][kk * 32 + q8];
      __builtin_amdgcn_s_setprio(1);
#pragma unroll
      for (int i = 0; i < 4; ++i)
#pragma unroll
        for (int j = 0; j < 2; ++j)
          acc[i][j] = __builtin_amdgcn_mfma_f32_16x16x32_bf16(aF[i], bF[j], acc[i][j], 0, 0, 0);
      __builtin_amdgcn_s_setprio(0);
    }
  }
#pragma unroll
  for (int i = 0; i < 4; ++i)
#pragma unroll
    for (int j = 0; j < 2; ++j) {
      const int n = n0 + wn + 16 * j + ln;
      const float bb = bias[n];
#pragma unroll
      for (int r = 0; r < 4; ++r) {
        const int m = m0 + wm + 16 * i + qd * 4 + r;
        Y[(size_t)m * DM + n] = f2bf(acc[i][j][r] + bb);
      }
    }
}

// ---------------- K^T builder with k-permutation baked in ----------------------
// Kt[(bh*64+d)][s_blk*128 + c'] = K[b][s_blk*128 + sigma(c')][h*64+d]
// sigma(c') = 16*(c'&7) + (c'>>3); matches the P-store layout in flash_attn.
__global__ __launch_bounds__(256)
void ktrans(const unsigned short* __restrict__ K, unsigned short* __restrict__ Kt) {
  __shared__ unsigned short T[128][72];
  const int tid = threadIdx.x;
  const int bh = blockIdx.y, b = bh >> 3, h = bh & 7;
  const int s0 = blockIdx.x * 128;
#pragma unroll
  for (int i = 0; i < 4; ++i) {                     // load tile [128 s][64 d]
    int cid = tid + i * 256;
    int r = cid >> 3, ch = (cid & 7) * 8;
    *(uint4*)&T[r][ch] =
        *(const uint4*)(K + (size_t)(b * S2v + s0 + r) * DM + h * HD + ch);
  }
  __syncthreads();
#pragma unroll
  for (int i = 0; i < 4; ++i) {                     // write [64 d][128 c']
    int cid = tid + i * 256;
    int d = cid >> 4, a = cid & 15;                 // c' = a*8 + k
    ushort4 v0, v1;
    v0.x = T[16 * 0 + a][d]; v0.y = T[16 * 1 + a][d];
    v0.z = T[16 * 2 + a][d]; v0.w = T[16 * 3 + a][d];
    v1.x = T[16 * 4 + a][d]; v1.y = T[16 * 5 + a][d];
    v1.z = T[16 * 6 + a][d]; v1.w = T[16 * 7 + a][d];
    unsigned short* o = Kt + ((size_t)(bh * HD + d)) * (size_t)S2v + s0 + a * 8;
    *(ushort4*)o = v0;
    *(ushort4*)(o + 4) = v1;
  }
}

// ---------------- flash attention (V = K), masked, static softmax --------------
// grid (S1/128, BSZ*NH), block 256: 4 waves x 32 Q-rows (2 subtiles of 16).
// Round-2: Round-0 staging skeleton + XCD swizzle (kept: FETCH 70->20MB) +
// MINIMAL single-set prefetch: only the K tile (4 x uint4 = 16 VGPR) + m2 are
// loaded into registers right after the staging barrier, consumed by the LDS
// write at the NEXT iteration top. No second register set, no rotate copies --
// round-1's nk/nv+rotate pushed the live set over the allocator target and
// spilled ~68 B/thread/iter to scratch (WRITE_SIZE 16->160MB, dur 65->99us).
// Vt stays in the stall path: after the swizzle it is an L2 hit (~200-300cy),
// not a 900cy HBM miss, so the exposed stall per iteration is small.
__global__ __launch_bounds__(256, 2)
void flash_attn(const unsigned short* __restrict__ Qb, const unsigned short* __restrict__ Kb,
                const unsigned short* __restrict__ Kt, const int* __restrict__ m1,
                const int* __restrict__ m2, float* __restrict__ attn) {
  __shared__ unsigned short Ks[128][72];
  __shared__ unsigned short Vts[64][136];
  __shared__ unsigned short Ps[4][32][136];
  __shared__ int m2s[128];

  const int tid = threadIdx.x;
  const int wv = tid >> 6, lane = tid & 63;
  const int ln = lane & 15, qd = lane >> 4, q8 = qd * 8;
  // XCD swizzle: lin = dispatch order; 64-block chunk per XCD -> 4 bh-panels/XCD
  const int lin = blockIdx.x + (blockIdx.y << 4);       // gridDim.x == 16
  const int lid = ((lin & 7) << 6) | (lin >> 3);        // bijective (512 % 8 == 0)
  const int bh = lid >> 4;
  const int b = bh >> 3, h = bh & 7;
  const int q0 = (lid & 15) << 7;

  // staging coordinates (per-thread, constant across iterations)
  const int rK = tid >> 3, cK = (tid & 7) * 8;          // K tile: 4 x uint4 / thread
  const int rV = tid >> 4, cV = (tid & 15) * 8;         // Vt tile: 4 x uint4 / thread
  const unsigned short* kbase = Kb + ((size_t)(b * S2v) + rK) * DM + h * HD + cK;
  const unsigned short* vbase = Kt + ((size_t)(bh * HD + rV)) * (size_t)S2v + cV;
  const int* m2base = m2 + b * S2v + (tid & 127);

  // Q fragments straight from global (one-time, L2-warm from proj_gemm)
  bf16x8 aQ[2][2];
#pragma unroll
  for (int t = 0; t < 2; ++t) {
    const size_t rbase =
        ((size_t)(b * S1v + q0 + wv * 32 + t * 16 + ln)) * DM + h * HD;
    aQ[t][0] = *(const bf16x8*)(Qb + rbase + q8);
    aQ[t][1] = *(const bf16x8*)(Qb + rbase + 32 + q8);
  }

  float acoef[2][4];                                // 0 if m1==0 (uniform row)
#pragma unroll
  for (int t = 0; t < 2; ++t)
#pragma unroll
    for (int r = 0; r < 4; ++r)
      acoef[t][r] = (m1[b * S1v + q0 + wv * 32 + t * 16 + qd * 4 + r] == 0) ? 0.f : 1.f;

  float lrow[2][4] = {};
  f32x4 O[2][4] = {};

  // prologue: prefetch tile-0 K + m2 into registers (single set, 17 VGPR)
  uint4 pk[4]; int pm = 0;
#pragma unroll
  for (int i = 0; i < 4; ++i)
    pk[i] = *(const uint4*)(kbase + (size_t)(i * 32) * DM);
  if (tid < 128) pm = m2base[0];

  for (int s0 = 0; s0 < S2v; s0 += 128) {
    __syncthreads();
#pragma unroll
    for (int i = 0; i < 4; ++i) *(uint4*)&Ks[rK + i * 32][cK] = pk[i];
    if (tid < 128) m2s[tid] = pm;
#pragma unroll
    for (int i = 0; i < 4; ++i) {                   // Vt tile: direct, L2-hit
      *(uint4*)&Vts[rV + i * 16][cV] =
          *(const uint4*)(vbase + s0 + (size_t)(i * 16) * (size_t)S2v);
    }
    __syncthreads();

    // prefetch NEXT K tile + m2 into the SAME registers (consumed above);
    // latency hides under QK + softmax + PV.  Wraps on last iter (unused).
    const int sn = (s0 + 128) & (S2v - 1);
#pragma unroll
    for (int i = 0; i < 4; ++i)
      pk[i] = *(const uint4*)(kbase + ((size_t)sn + (size_t)(i * 32)) * DM);
    if (tid < 128) pm = m2base[sn];

    // S = Q K^T : two 16-row subtiles share the K fragments
    f32x4 sc[2][8];
    __builtin_amdgcn_s_setprio(1);
#pragma unroll
    for (int j = 0; j < 8; ++j) {
      const bf16x8 b0 = *(const bf16x8*)&Ks[16 * j + ln][q8];
      const bf16x8 b1 = *(const bf16x8*)&Ks[16 * j + ln][32 + q8];
#pragma unroll
      for (int t = 0; t < 2; ++t) {
        f32x4 z = {};
        z = __builtin_amdgcn_mfma_f32_16x16x32_bf16(aQ[t][0], b0, z, 0, 0, 0);
        sc[t][j] = __builtin_amdgcn_mfma_f32_16x16x32_bf16(aQ[t][1], b1, z, 0, 0, 0);
      }
    }
    __builtin_amdgcn_s_setprio(0);

    float moff[8];
#pragma unroll
    for (int j = 0; j < 8; ++j)
      moff[j] = (m2s[16 * j + ln] != 0) ? 0.f : NEGB;

    // p = exp2( a * (sc*SC_L2E + moff) + CBIAS ); masked->0, uniform rows->2^CBIAS
#pragma unroll
    for (int t = 0; t < 2; ++t)
#pragma unroll
      for (int j = 0; j < 8; ++j)
#pragma unroll
        for (int r = 0; r < 4; ++r) {
          const float e = fmaf(acoef[t][r], fmaf(sc[t][j][r], SC_L2E, moff[j]), CBIAS);
          const float p = __builtin_amdgcn_exp2f(e);
          lrow[t][r] += p;
          sc[t][j][r] = p;
        }

    // pack: row q, cols c' = ln*8 .. ln*8+7  (one ds_write_b128 per (t,r))
#pragma unroll
    for (int t = 0; t < 2; ++t)
#pragma unroll
      for (int r = 0; r < 4; ++r) {
        uint4 dw;
        dw.x = __builtin_amdgcn_perm(asu(sc[t][1][r]), asu(sc[t][0][r]), 0x07060302u);
        dw.y = __builtin_amdgcn_perm(asu(sc[t][3][r]), asu(sc[t][2][r]), 0x07060302u);
        dw.z = __builtin_amdgcn_perm(asu(sc[t][5][r]), asu(sc[t][4][r]), 0x07060302u);
        dw.w = __builtin_amdgcn_perm(asu(sc[t][7][r]), asu(sc[t][6][r]), 0x07060302u);
        *(uint4*)&Ps[wv][t * 16 + qd * 4 + r][ln * 8] = dw;
      }
    // order + drain the P stores before the A-fragment reads (wave-private tile)
    __asm__ volatile("s_waitcnt lgkmcnt(0)" ::: "memory");

    // O += P V : subtiles share the V fragments
    __builtin_amdgcn_s_setprio(1);
#pragma unroll
    for (int kk = 0; kk < 4; ++kk) {
      const bf16x8 aP0 = *(const bf16x8*)&Ps[wv][ln][kk * 32 + q8];
      const bf16x8 aP1 = *(const bf16x8*)&Ps[wv][16 + ln][kk * 32 + q8];
#pragma unroll
      for (int jn = 0; jn < 4; ++jn) {
        const bf16x8 bV = *(const bf16x8*)&Vts[16 * jn + ln][kk * 32 + q8];
        O[0][jn] = __builtin_amdgcn_mfma_f32_16x16x32_bf16(aP0, bV, O[0][jn], 0, 0, 0);
        O[1][jn] = __builtin_amdgcn_mfma_f32_16x16x32_bf16(aP1, bV, O[1][jn], 0, 0, 0);
      }
    }
    __builtin_amdgcn_s_setprio(0);
  }

#pragma unroll
  for (int t = 0; t < 2; ++t)
#pragma unroll
    for (int r = 0; r < 4; ++r) {
      float l = lrow[t][r];
#pragma unroll
      for (int msk = 1; msk < 16; msk <<= 1) l += __shfl_xor(l, msk, 64);
      const float inv = l > 0.f ? 1.0f / l : 0.f;
      const int m = q0 + wv * 32 + t * 16 + qd * 4 + r;
#pragma unroll
      for (int jn = 0; jn < 4; ++jn)
        attn[((size_t)(b * S1v + m)) * DM + h * HD + 16 * jn + ln] = O[t][jn][r] * inv;
    }
}

// ---------------- fused LN2(attn + LN1(attn + modal1)) ------------------------
__global__ __launch_bounds__(128)
void ln_fused(const float* __restrict__ attn, const float* __restrict__ modal1,
              const float* __restrict__ g1, const float* __restrict__ b1,
              const float* __restrict__ g2, const float* __restrict__ b2,
              float* __restrict__ out) {
  __shared__ float red[4];
  const int row = blockIdx.x, t = threadIdx.x;
  const size_t base = (size_t)row * DM + t * 4;
  const float4 a = *(const float4*)(attn + base);
  const float4 mo = *(const float4*)(modal1 + base);
  float av[4] = { a.x, a.y, a.z, a.w };
  float x[4] = { a.x + mo.x, a.y + mo.y, a.z + mo.z, a.w + mo.w };
  float s = 0.f, q = 0.f;
#pragma unroll
  for (int i = 0; i < 4; ++i) { s += x[i]; q += x[i] * x[i]; }
#pragma unroll
  for (int m = 1; m < 64; m <<= 1) { s += __shfl_xor(s, m, 64); q += __shfl_xor(q, m, 64); }
  if ((t & 63) == 0) { red[t >> 6] = s; red[2 + (t >> 6)] = q; }
  __syncthreads();
  s = red[0] + red[1]; q = red[2] + red[3];
  const float mu = s * (1.0f / DM);
  const float rinv = rsqrtf(q * (1.0f / DM) - mu * mu + 1e-5f);
  const int c = t * 4;
  const float4 G1 = *(const float4*)(g1 + c), B1 = *(const float4*)(b1 + c);
  const float gg1[4] = { G1.x, G1.y, G1.z, G1.w }, bb1[4] = { B1.x, B1.y, B1.z, B1.w };
  float y[4];
  float s2 = 0.f, q2 = 0.f;
#pragma unroll
  for (int i = 0; i < 4; ++i) {
    y[i] = av[i] + (x[i] - mu) * rinv * gg1[i] + bb1[i];
    s2 += y[i]; q2 += y[i] * y[i];
  }
#pragma unroll
  for (int m = 1; m < 64; m <<= 1) { s2 += __shfl_xor(s2, m, 64); q2 += __shfl_xor(q2, m, 64); }
  __syncthreads();
  if ((t & 63) == 0) { red[t >> 6] = s2; red[2 + (t >> 6)] = q2; }
  __syncthreads();
  s2 = red[0] + red[1]; q2 = red[2] + red[3];
  const float mu2 = s2 * (1.0f / DM);
  const float rinv2 = rsqrtf(q2 * (1.0f / DM) - mu2 * mu2 + 1e-5f);
  const float4 G2 = *(const float4*)(g2 + c), B2 = *(const float4*)(b2 + c);
  float4 o;
  o.x = (y[0] - mu2) * rinv2 * G2.x + B2.x;
  o.y = (y[1] - mu2) * rinv2 * G2.y + B2.y;
  o.z = (y[2] - mu2) * rinv2 * G2.z + B2.z;
  o.w = (y[3] - mu2) * rinv2 * G2.w + B2.w;
  *(float4*)(out + base) = o;
}

extern "C" void kernel_launch(void* const* d_in, const int* in_sizes, int n_in,
                              void* d_out, int out_size, void* d_ws, size_t ws_size,
                              hipStream_t stream) {
  const float* modal1 = (const float*)d_in[0];
  const float* modal2 = (const float*)d_in[1];
  const int*   m1     = (const int*)d_in[2];
  const int*   m2     = (const int*)d_in[3];
  const float* Wq     = (const float*)d_in[4];
  const float* bq     = (const float*)d_in[5];
  const float* Wkv    = (const float*)d_in[6];
  const float* bkv    = (const float*)d_in[7];
  const float* g1     = (const float*)d_in[8];
  const float* b1     = (const float*)d_in[9];
  // d_in[10..13] = FFN weights -> output discarded by the reference; skipped.
  const float* g2     = (const float*)d_in[14];
  const float* b2     = (const float*)d_in[15];
  float* out = (float*)d_out;

  char* ws = (char*)d_ws;
  unsigned short* q_bf  = (unsigned short*)(ws);                 //  8 MB
  unsigned short* k_bf  = (unsigned short*)(ws + 8388608);       //  8 MB
  unsigned short* kt_bf = (unsigned short*)(ws + 16777216);      //  8 MB
  unsigned short* wqt   = (unsigned short*)(ws + 25165824);      // 512 KB
  unsigned short* wkt   = (unsigned short*)(ws + 25690112);      // 512 KB
  float*          attn  = (float*)(ws + 26214400);               // 16 MB

  dim3 tb(32, 8);
  wtrans<<<dim3(16, 16), tb, 0, stream>>>(Wq, wqt);
  wtrans<<<dim3(16, 16), tb, 0, stream>>>(Wkv, wkt);
  proj_gemm<<<dim3(64, 4), 512, 0, stream>>>(modal1, wqt, bq, q_bf);
  proj_gemm<<<dim3(64, 4), 512, 0, stream>>>(modal2, wkt, bkv, k_bf);
  ktrans<<<dim3(16, 32), 256, 0, stream>>>(k_bf, kt_bf);
  flash_attn<<<dim3(16, 32), 256, 0, stream>>>(q_bf, k_bf, kt_bf, m1, m2, attn);
  ln_fused<<<dim3(8192), 128, 0, stream>>>(attn, modal1, g1, b1, g2, b2, out);
}

// Round 3
// 203.166 us; speedup vs baseline: 1.2021x; 1.1038x over previous
//
#include <hip/hip_runtime.h>
#include <hip/hip_bf16.h>

#define BSZ 4
#define S1v 2048
#define S2v 2048
#define DM 512
#define NH 8
#define HD 64
#define SCALE 0.044194173824159216f
#define L2E 1.4426950408889634f
#define SC_L2E (0.044194173824159216f * 1.4426950408889634f)
#define CBIAS 0.0028152f   /* log2(1+2^-9): centers truncating bf16 pack */
#define NEGB (-1e30f)

typedef __bf16 bf16x8 __attribute__((ext_vector_type(8)));
typedef float f32x4 __attribute__((ext_vector_type(4)));

__device__ __forceinline__ unsigned short f2bf(float f) {
  union { float f; unsigned u; } v; v.f = f;
  unsigned r = v.u + 0x7FFFu + ((v.u >> 16) & 1u);
  return (unsigned short)(r >> 16);
}
__device__ __forceinline__ unsigned asu(float f) {
  union { float f; unsigned u; } v; v.f = f; return v.u;
}

// ---------------- weight transpose + cast: Wt[n][k] = bf16(W[k][n]) ------------
__global__ __launch_bounds__(256)
void wtrans(const float* __restrict__ W, unsigned short* __restrict__ Wt) {
  __shared__ float tile[32][33];
  const int tx = threadIdx.x, ty = threadIdx.y;     // block (32,8)
  const int n0 = blockIdx.x * 32, k0 = blockIdx.y * 32;
#pragma unroll
  for (int i = 0; i < 32; i += 8)
    tile[ty + i][tx] = W[(size_t)(k0 + ty + i) * DM + n0 + tx];
  __syncthreads();
#pragma unroll
  for (int i = 0; i < 32; i += 8)
    Wt[(size_t)(n0 + ty + i) * DM + k0 + tx] = f2bf(tile[tx][ty + i]);
}

// ---------------- projection GEMM: Y(bf16)[8192x512] = X(f32) @ W + bias -------
// Round-0 proven version (256 threads), byte-for-byte.
__global__ __launch_bounds__(256)
void proj_gemm(const float* __restrict__ X, const unsigned short* __restrict__ Wt,
               const float* __restrict__ bias, unsigned short* __restrict__ Y) {
  __shared__ unsigned short Xs[128][72];
  __shared__ unsigned short Ws[128][72];
  const int tid = threadIdx.x;
  const int wv = tid >> 6, lane = tid & 63;
  const int ln = lane & 15, qd = lane >> 4, q8 = qd * 8;
  const int wm = (wv >> 1) * 64, wn = (wv & 1) * 64;
  const int m0 = blockIdx.x * 128, n0 = blockIdx.y * 128;
  f32x4 acc[4][4] = {};
  for (int k0 = 0; k0 < DM; k0 += 64) {
    __syncthreads();
#pragma unroll
    for (int i = 0; i < 8; ++i) {                   // X tile 128x64 f32 -> bf16
      int cid = tid + i * 256;
      int r = cid >> 4, c4 = (cid & 15) * 4;
      const float4 v = *(const float4*)(X + (size_t)(m0 + r) * DM + k0 + c4);
      ushort4 bv;
      bv.x = f2bf(v.x); bv.y = f2bf(v.y); bv.z = f2bf(v.z); bv.w = f2bf(v.w);
      *(ushort4*)&Xs[r][c4] = bv;
    }
#pragma unroll
    for (int i = 0; i < 4; ++i) {                   // Wt tile 128x64 bf16 copy
      int cid = tid + i * 256;
      int r = cid >> 3, ch = (cid & 7) * 8;
      *(uint4*)&Ws[r][ch] = *(const uint4*)(Wt + (size_t)(n0 + r) * DM + k0 + ch);
    }
    __syncthreads();
#pragma unroll
    for (int kk = 0; kk < 2; ++kk) {
      bf16x8 aF[4], bF[4];
#pragma unroll
      for (int i = 0; i < 4; ++i)
        aF[i] = *(const bf16x8*)&Xs[wm + 16 * i + ln][kk * 32 + q8];
#pragma unroll
      for (int j = 0; j < 4; ++j)
        bF[j] = *(const bf16x8*)&Ws[wn + 16 * j + ln][kk * 32 + q8];
#pragma unroll
      for (int i = 0; i < 4; ++i)
#pragma unroll
        for (int j = 0; j < 4; ++j)
          acc[i][j] = __builtin_amdgcn_mfma_f32_16x16x32_bf16(aF[i], bF[j], acc[i][j], 0, 0, 0);
    }
  }
#pragma unroll
  for (int i = 0; i < 4; ++i)
#pragma unroll
    for (int j = 0; j < 4; ++j) {
      const int n = n0 + wn + 16 * j + ln;
      const float bb = bias[n];
#pragma unroll
      for (int r = 0; r < 4; ++r) {
        const int m = m0 + wm + 16 * i + qd * 4 + r;
        Y[(size_t)m * DM + n] = f2bf(acc[i][j][r] + bb);
      }
    }
}

// ---------------- K^T builder with k-permutation baked in ----------------------
// Kt[(bh*64+d)][s_blk*128 + c'] = K[b][s_blk*128 + sigma(c')][h*64+d]
// sigma(c') = 16*(c'&7) + (c'>>3); matches the P-store layout in flash_attn.
__global__ __launch_bounds__(256)
void ktrans(const unsigned short* __restrict__ K, unsigned short* __restrict__ Kt) {
  __shared__ unsigned short T[128][72];
  const int tid = threadIdx.x;
  const int bh = blockIdx.y, b = bh >> 3, h = bh & 7;
  const int s0 = blockIdx.x * 128;
#pragma unroll
  for (int i = 0; i < 4; ++i) {                     // load tile [128 s][64 d]
    int cid = tid + i * 256;
    int r = cid >> 3, ch = (cid & 7) * 8;
    *(uint4*)&T[r][ch] =
        *(const uint4*)(K + (size_t)(b * S2v + s0 + r) * DM + h * HD + ch);
  }
  __syncthreads();
#pragma unroll
  for (int i = 0; i < 4; ++i) {                     // write [64 d][128 c']
    int cid = tid + i * 256;
    int d = cid >> 4, a = cid & 15;                 // c' = a*8 + k
    ushort4 v0, v1;
    v0.x = T[16 * 0 + a][d]; v0.y = T[16 * 1 + a][d];
    v0.z = T[16 * 2 + a][d]; v0.w = T[16 * 3 + a][d];
    v1.x = T[16 * 4 + a][d]; v1.y = T[16 * 5 + a][d];
    v1.z = T[16 * 6 + a][d]; v1.w = T[16 * 7 + a][d];
    unsigned short* o = Kt + ((size_t)(bh * HD + d)) * (size_t)S2v + s0 + a * 8;
    *(ushort4*)o = v0;
    *(ushort4*)(o + 4) = v1;
  }
}

// ---------------- flash attention (V = K), masked, static softmax --------------
// grid (S1/128, BSZ*NH), block 256: 4 waves x 32 Q-rows (2 subtiles of 16).
// Round-3: EXACT Round-0 body (65.5us verified) + ONE change: bijective XCD
// swizzle (proven -53MB FETCH in R2). No setprio, no register prefetch --
// both were in the R1/R2 bundles that ADDED ~12us of stall at equal busy-time
// (setprio starves the co-resident block's staging issue in this lockstep
// structure, per m190; register prefetch serialized staging for no gain).
__global__ __launch_bounds__(256, 2)
void flash_attn(const unsigned short* __restrict__ Qb, const unsigned short* __restrict__ Kb,
                const unsigned short* __restrict__ Kt, const int* __restrict__ m1,
                const int* __restrict__ m2, float* __restrict__ attn) {
  __shared__ unsigned short Ks[128][72];
  __shared__ unsigned short Vts[64][136];
  __shared__ unsigned short Ps[4][32][136];
  __shared__ int m2s[128];

  const int tid = threadIdx.x;
  const int wv = tid >> 6, lane = tid & 63;
  const int ln = lane & 15, qd = lane >> 4, q8 = qd * 8;
  // XCD swizzle: dispatch order lin round-robins XCDs; give each XCD a
  // contiguous 64-lid chunk = 4 bh-panels (~3MB K+Kt+Q < 4MB L2).
  const int lin = blockIdx.x + (blockIdx.y << 4);       // gridDim.x == 16
  const int lid = ((lin & 7) << 6) | (lin >> 3);        // bijective (512 % 8 == 0)
  const int bh = lid >> 4;
  const int b = bh >> 3, h = bh & 7;
  const int q0 = (lid & 15) << 7;

  // Q fragments straight from global (one-time, L2-warm from proj_gemm)
  bf16x8 aQ[2][2];
#pragma unroll
  for (int t = 0; t < 2; ++t) {
    const size_t rbase =
        ((size_t)(b * S1v + q0 + wv * 32 + t * 16 + ln)) * DM + h * HD;
    aQ[t][0] = *(const bf16x8*)(Qb + rbase + q8);
    aQ[t][1] = *(const bf16x8*)(Qb + rbase + 32 + q8);
  }

  float acoef[2][4];                                // 0 if m1==0 (uniform row)
#pragma unroll
  for (int t = 0; t < 2; ++t)
#pragma unroll
    for (int r = 0; r < 4; ++r)
      acoef[t][r] = (m1[b * S1v + q0 + wv * 32 + t * 16 + qd * 4 + r] == 0) ? 0.f : 1.f;

  float lrow[2][4] = {};
  f32x4 O[2][4] = {};

  for (int s0 = 0; s0 < S2v; s0 += 128) {
    __syncthreads();
#pragma unroll
    for (int i = 0; i < 4; ++i) {                   // K tile 128x64
      int cid = tid + i * 256;
      int r = cid >> 3, ch = (cid & 7) * 8;
      *(uint4*)&Ks[r][ch] =
          *(const uint4*)(Kb + ((size_t)(b * S2v + s0 + r)) * DM + h * HD + ch);
    }
#pragma unroll
    for (int i = 0; i < 4; ++i) {                   // V^T tile 64x128 (k-permuted)
      int cid = tid + i * 256;
      int r = cid >> 4, ch = (cid & 15) * 8;
      *(uint4*)&Vts[r][ch] =
          *(const uint4*)(Kt + ((size_t)(bh * HD + r)) * (size_t)S2v + s0 + ch);
    }
    if (tid < 128) m2s[tid] = m2[b * S2v + s0 + tid];
    __syncthreads();

    // S = Q K^T : two 16-row subtiles share the K fragments
    f32x4 sc[2][8];
#pragma unroll
    for (int j = 0; j < 8; ++j) {
      const bf16x8 b0 = *(const bf16x8*)&Ks[16 * j + ln][q8];
      const bf16x8 b1 = *(const bf16x8*)&Ks[16 * j + ln][32 + q8];
#pragma unroll
      for (int t = 0; t < 2; ++t) {
        f32x4 z = {};
        z = __builtin_amdgcn_mfma_f32_16x16x32_bf16(aQ[t][0], b0, z, 0, 0, 0);
        sc[t][j] = __builtin_amdgcn_mfma_f32_16x16x32_bf16(aQ[t][1], b1, z, 0, 0, 0);
      }
    }

    float moff[8];
#pragma unroll
    for (int j = 0; j < 8; ++j)
      moff[j] = (m2s[16 * j + ln] != 0) ? 0.f : NEGB;

    // p = exp2( a * (sc*SC_L2E + moff) + CBIAS ); masked->0, uniform rows->2^CBIAS
#pragma unroll
    for (int t = 0; t < 2; ++t)
#pragma unroll
      for (int j = 0; j < 8; ++j)
#pragma unroll
        for (int r = 0; r < 4; ++r) {
          const float e = fmaf(acoef[t][r], fmaf(sc[t][j][r], SC_L2E, moff[j]), CBIAS);
          const float p = __builtin_amdgcn_exp2f(e);
          lrow[t][r] += p;
          sc[t][j][r] = p;
        }

    // pack: row q, cols c' = ln*8 .. ln*8+7  (one ds_write_b128 per (t,r))
#pragma unroll
    for (int t = 0; t < 2; ++t)
#pragma unroll
      for (int r = 0; r < 4; ++r) {
        uint4 dw;
        dw.x = __builtin_amdgcn_perm(asu(sc[t][1][r]), asu(sc[t][0][r]), 0x07060302u);
        dw.y = __builtin_amdgcn_perm(asu(sc[t][3][r]), asu(sc[t][2][r]), 0x07060302u);
        dw.z = __builtin_amdgcn_perm(asu(sc[t][5][r]), asu(sc[t][4][r]), 0x07060302u);
        dw.w = __builtin_amdgcn_perm(asu(sc[t][7][r]), asu(sc[t][6][r]), 0x07060302u);
        *(uint4*)&Ps[wv][t * 16 + qd * 4 + r][ln * 8] = dw;
      }
    // order + drain the P stores before the A-fragment reads (wave-private tile)
    __asm__ volatile("s_waitcnt lgkmcnt(0)" ::: "memory");

    // O += P V : subtiles share the V fragments
#pragma unroll
    for (int kk = 0; kk < 4; ++kk) {
      const bf16x8 aP0 = *(const bf16x8*)&Ps[wv][ln][kk * 32 + q8];
      const bf16x8 aP1 = *(const bf16x8*)&Ps[wv][16 + ln][kk * 32 + q8];
#pragma unroll
      for (int jn = 0; jn < 4; ++jn) {
        const bf16x8 bV = *(const bf16x8*)&Vts[16 * jn + ln][kk * 32 + q8];
        O[0][jn] = __builtin_amdgcn_mfma_f32_16x16x32_bf16(aP0, bV, O[0][jn], 0, 0, 0);
        O[1][jn] = __builtin_amdgcn_mfma_f32_16x16x32_bf16(aP1, bV, O[1][jn], 0, 0, 0);
      }
    }
  }

#pragma unroll
  for (int t = 0; t < 2; ++t)
#pragma unroll
    for (int r = 0; r < 4; ++r) {
      float l = lrow[t][r];
#pragma unroll
      for (int msk = 1; msk < 16; msk <<= 1) l += __shfl_xor(l, msk, 64);
      const float inv = l > 0.f ? 1.0f / l : 0.f;
      const int m = q0 + wv * 32 + t * 16 + qd * 4 + r;
#pragma unroll
      for (int jn = 0; jn < 4; ++jn)
        attn[((size_t)(b * S1v + m)) * DM + h * HD + 16 * jn + ln] = O[t][jn][r] * inv;
    }
}

// ---------------- fused LN2(attn + LN1(attn + modal1)) ------------------------
__global__ __launch_bounds__(128)
void ln_fused(const float* __restrict__ attn, const float* __restrict__ modal1,
              const float* __restrict__ g1, const float* __restrict__ b1,
              const float* __restrict__ g2, const float* __restrict__ b2,
              float* __restrict__ out) {
  __shared__ float red[4];
  const int row = blockIdx.x, t = threadIdx.x;
  const size_t base = (size_t)row * DM + t * 4;
  const float4 a = *(const float4*)(attn + base);
  const float4 mo = *(const float4*)(modal1 + base);
  float av[4] = { a.x, a.y, a.z, a.w };
  float x[4] = { a.x + mo.x, a.y + mo.y, a.z + mo.z, a.w + mo.w };
  float s = 0.f, q = 0.f;
#pragma unroll
  for (int i = 0; i < 4; ++i) { s += x[i]; q += x[i] * x[i]; }
#pragma unroll
  for (int m = 1; m < 64; m <<= 1) { s += __shfl_xor(s, m, 64); q += __shfl_xor(q, m, 64); }
  if ((t & 63) == 0) { red[t >> 6] = s; red[2 + (t >> 6)] = q; }
  __syncthreads();
  s = red[0] + red[1]; q = red[2] + red[3];
  const float mu = s * (1.0f / DM);
  const float rinv = rsqrtf(q * (1.0f / DM) - mu * mu + 1e-5f);
  const int c = t * 4;
  const float4 G1 = *(const float4*)(g1 + c), B1 = *(const float4*)(b1 + c);
  const float gg1[4] = { G1.x, G1.y, G1.z, G1.w }, bb1[4] = { B1.x, B1.y, B1.z, B1.w };
  float y[4];
  float s2 = 0.f, q2 = 0.f;
#pragma unroll
  for (int i = 0; i < 4; ++i) {
    y[i] = av[i] + (x[i] - mu) * rinv * gg1[i] + bb1[i];
    s2 += y[i]; q2 += y[i] * y[i];
  }
#pragma unroll
  for (int m = 1; m < 64; m <<= 1) { s2 += __shfl_xor(s2, m, 64); q2 += __shfl_xor(q2, m, 64); }
  __syncthreads();
  if ((t & 63) == 0) { red[t >> 6] = s2; red[2 + (t >> 6)] = q2; }
  __syncthreads();
  s2 = red[0] + red[1]; q2 = red[2] + red[3];
  const float mu2 = s2 * (1.0f / DM);
  const float rinv2 = rsqrtf(q2 * (1.0f / DM) - mu2 * mu2 + 1e-5f);
  const float4 G2 = *(const float4*)(g2 + c), B2 = *(const float4*)(b2 + c);
  float4 o;
  o.x = (y[0] - mu2) * rinv2 * G2.x + B2.x;
  o.y = (y[1] - mu2) * rinv2 * G2.y + B2.y;
  o.z = (y[2] - mu2) * rinv2 * G2.z + B2.z;
  o.w = (y[3] - mu2) * rinv2 * G2.w + B2.w;
  *(float4*)(out + base) = o;
}

extern "C" void kernel_launch(void* const* d_in, const int* in_sizes, int n_in,
                              void* d_out, int out_size, void* d_ws, size_t ws_size,
                              hipStream_t stream) {
  const float* modal1 = (const float*)d_in[0];
  const float* modal2 = (const float*)d_in[1];
  const int*   m1     = (const int*)d_in[2];
  const int*   m2     = (const int*)d_in[3];
  const float* Wq     = (const float*)d_in[4];
  const float* bq     = (const float*)d_in[5];
  const float* Wkv    = (const float*)d_in[6];
  const float* bkv    = (const float*)d_in[7];
  const float* g1     = (const float*)d_in[8];
  const float* b1     = (const float*)d_in[9];
  // d_in[10..13] = FFN weights -> output discarded by the reference; skipped.
  const float* g2     = (const float*)d_in[14];
  const float* b2     = (const float*)d_in[15];
  float* out = (float*)d_out;

  char* ws = (char*)d_ws;
  unsigned short* q_bf  = (unsigned short*)(ws);                 //  8 MB
  unsigned short* k_bf  = (unsigned short*)(ws + 8388608);       //  8 MB
  unsigned short* kt_bf = (unsigned short*)(ws + 16777216);      //  8 MB
  unsigned short* wqt   = (unsigned short*)(ws + 25165824);      // 512 KB
  unsigned short* wkt   = (unsigned short*)(ws + 25690112);      // 512 KB
  float*          attn  = (float*)(ws + 26214400);               // 16 MB

  dim3 tb(32, 8);
  wtrans<<<dim3(16, 16), tb, 0, stream>>>(Wq, wqt);
  wtrans<<<dim3(16, 16), tb, 0, stream>>>(Wkv, wkt);
  proj_gemm<<<dim3(64, 4), 256, 0, stream>>>(modal1, wqt, bq, q_bf);
  proj_gemm<<<dim3(64, 4), 256, 0, stream>>>(modal2, wkt, bkv, k_bf);
  ktrans<<<dim3(16, 32), 256, 0, stream>>>(k_bf, kt_bf);
  flash_attn<<<dim3(16, 32), 256, 0, stream>>>(q_bf, k_bf, kt_bf, m1, m2, attn);
  ln_fused<<<dim3(8192), 128, 0, stream>>>(attn, modal1, g1, b1, g2, b2, out);
}

// Round 5
// 201.478 us; speedup vs baseline: 1.2121x; 1.0084x over previous
//
#include <hip/hip_runtime.h>
#include <hip/hip_bf16.h>

#define BSZ 4
#define S1v 2048
#define S2v 2048
#define DM 512
#define NH 8
#define HD 64
#define SCALE 0.044194173824159216f
#define L2E 1.4426950408889634f
#define SC_L2E (0.044194173824159216f * 1.4426950408889634f)
#define CBIAS 0.0028152f   /* log2(1+2^-9): centers truncating bf16 pack */
#define NEGB (-1e30f)

typedef __bf16 bf16x8 __attribute__((ext_vector_type(8)));
typedef float f32x4 __attribute__((ext_vector_type(4)));

__device__ __forceinline__ unsigned short f2bf(float f) {
  union { float f; unsigned u; } v; v.f = f;
  unsigned r = v.u + 0x7FFFu + ((v.u >> 16) & 1u);
  return (unsigned short)(r >> 16);
}
__device__ __forceinline__ unsigned asu(float f) {
  union { float f; unsigned u; } v; v.f = f; return v.u;
}

// ---------------- weight transpose + cast: Wt[n][k] = bf16(W[k][n]) ------------
__global__ __launch_bounds__(256)
void wtrans(const float* __restrict__ W, unsigned short* __restrict__ Wt) {
  __shared__ float tile[32][33];
  const int tx = threadIdx.x, ty = threadIdx.y;     // block (32,8)
  const int n0 = blockIdx.x * 32, k0 = blockIdx.y * 32;
#pragma unroll
  for (int i = 0; i < 32; i += 8)
    tile[ty + i][tx] = W[(size_t)(k0 + ty + i) * DM + n0 + tx];
  __syncthreads();
#pragma unroll
  for (int i = 0; i < 32; i += 8)
    Wt[(size_t)(n0 + ty + i) * DM + k0 + tx] = f2bf(tile[tx][ty + i]);
}

// ---------------- projection GEMM: Y(bf16)[8192x512] = X(f32) @ W + bias -------
// Round-0 proven version (256 threads), byte-for-byte.
__global__ __launch_bounds__(256)
void proj_gemm(const float* __restrict__ X, const unsigned short* __restrict__ Wt,
               const float* __restrict__ bias, unsigned short* __restrict__ Y) {
  __shared__ unsigned short Xs[128][72];
  __shared__ unsigned short Ws[128][72];
  const int tid = threadIdx.x;
  const int wv = tid >> 6, lane = tid & 63;
  const int ln = lane & 15, qd = lane >> 4, q8 = qd * 8;
  const int wm = (wv >> 1) * 64, wn = (wv & 1) * 64;
  const int m0 = blockIdx.x * 128, n0 = blockIdx.y * 128;
  f32x4 acc[4][4] = {};
  for (int k0 = 0; k0 < DM; k0 += 64) {
    __syncthreads();
#pragma unroll
    for (int i = 0; i < 8; ++i) {                   // X tile 128x64 f32 -> bf16
      int cid = tid + i * 256;
      int r = cid >> 4, c4 = (cid & 15) * 4;
      const float4 v = *(const float4*)(X + (size_t)(m0 + r) * DM + k0 + c4);
      ushort4 bv;
      bv.x = f2bf(v.x); bv.y = f2bf(v.y); bv.z = f2bf(v.z); bv.w = f2bf(v.w);
      *(ushort4*)&Xs[r][c4] = bv;
    }
#pragma unroll
    for (int i = 0; i < 4; ++i) {                   // Wt tile 128x64 bf16 copy
      int cid = tid + i * 256;
      int r = cid >> 3, ch = (cid & 7) * 8;
      *(uint4*)&Ws[r][ch] = *(const uint4*)(Wt + (size_t)(n0 + r) * DM + k0 + ch);
    }
    __syncthreads();
#pragma unroll
    for (int kk = 0; kk < 2; ++kk) {
      bf16x8 aF[4], bF[4];
#pragma unroll
      for (int i = 0; i < 4; ++i)
        aF[i] = *(const bf16x8*)&Xs[wm + 16 * i + ln][kk * 32 + q8];
#pragma unroll
      for (int j = 0; j < 4; ++j)
        bF[j] = *(const bf16x8*)&Ws[wn + 16 * j + ln][kk * 32 + q8];
#pragma unroll
      for (int i = 0; i < 4; ++i)
#pragma unroll
        for (int j = 0; j < 4; ++j)
          acc[i][j] = __builtin_amdgcn_mfma_f32_16x16x32_bf16(aF[i], bF[j], acc[i][j], 0, 0, 0);
    }
  }
#pragma unroll
  for (int i = 0; i < 4; ++i)
#pragma unroll
    for (int j = 0; j < 4; ++j) {
      const int n = n0 + wn + 16 * j + ln;
      const float bb = bias[n];
#pragma unroll
      for (int r = 0; r < 4; ++r) {
        const int m = m0 + wm + 16 * i + qd * 4 + r;
        Y[(size_t)m * DM + n] = f2bf(acc[i][j][r] + bb);
      }
    }
}

// ---------------- K^T builder with PV-label permutation baked in ---------------
// flash_attn's swapped QK^T leaves lane (ln,qd) holding P[q][k = 16j+4qd+r].
// Its PV A-fragment slot (kk, e) corresponds to label c = kk*32 + qd*8 + e.
// V must be staged with its rows in label order: col c holds original row
// u(c) = 16*(c>>5) + 4*((c>>3)&3) + 64*((c>>2)&1) + (c&3).
// For c = a*8 + w:  u = 16*(a>>2) + 4*(a&3) + 64*(w>>2) + (w&3)
//   -> v0 = rows base..base+3, v1 = rows base+64..base+67, base=16*(a>>2)+4*(a&3).
__global__ __launch_bounds__(256)
void ktrans(const unsigned short* __restrict__ K, unsigned short* __restrict__ Kt) {
  __shared__ unsigned short T[128][72];
  const int tid = threadIdx.x;
  const int bh = blockIdx.y, b = bh >> 3, h = bh & 7;
  const int s0 = blockIdx.x * 128;
#pragma unroll
  for (int i = 0; i < 4; ++i) {                     // load tile [128 s][64 d]
    int cid = tid + i * 256;
    int r = cid >> 3, ch = (cid & 7) * 8;
    *(uint4*)&T[r][ch] =
        *(const uint4*)(K + (size_t)(b * S2v + s0 + r) * DM + h * HD + ch);
  }
  __syncthreads();
#pragma unroll
  for (int i = 0; i < 4; ++i) {                     // write [64 d][128 c]
    int cid = tid + i * 256;
    int d = cid >> 4, a = cid & 15;
    const int base = 16 * (a >> 2) + 4 * (a & 3);
    ushort4 v0, v1;
    v0.x = T[base + 0][d]; v0.y = T[base + 1][d];
    v0.z = T[base + 2][d]; v0.w = T[base + 3][d];
    v1.x = T[base + 64][d]; v1.y = T[base + 65][d];
    v1.z = T[base + 66][d]; v1.w = T[base + 67][d];
    unsigned short* o = Kt + ((size_t)(bh * HD + d)) * (size_t)S2v + s0 + a * 8;
    *(ushort4*)o = v0;
    *(ushort4*)(o + 4) = v1;
  }
}

// ---------------- flash attention (V = K), masked, static softmax --------------
// grid (S1/128, BSZ*NH), block 256: 4 waves x 32 Q-rows (2 subtiles of 16).
// Round-5 (= Round-4 resubmit; R4 bench was an infra failure, source re-audited):
// SWAPPED QK^T (S^T = mfma(K,Q)) so each lane's P values are exactly its own
// PV A-fragment (label permutation baked into ktrans).  The Ps LDS round-trip
// (8 writes + 8 reads/wave-iter + lgkmcnt(0) full stop) is GONE: -29% LDS-pipe
// ops, LDS 71.2KB -> 36.4KB -> 3 blocks/CU.
__global__ __launch_bounds__(256, 3)
void flash_attn(const unsigned short* __restrict__ Qb, const unsigned short* __restrict__ Kb,
                const unsigned short* __restrict__ Kt, const int* __restrict__ m1,
                const int* __restrict__ m2, float* __restrict__ attn) {
  __shared__ unsigned short Ks[128][72];
  __shared__ unsigned short Vts[64][136];
  __shared__ float m2f[128];

  const int tid = threadIdx.x;
  const int wv = tid >> 6, lane = tid & 63;
  const int ln = lane & 15, qd = lane >> 4, q8 = qd * 8;
  // XCD swizzle (kept: FETCH 70->12.4MB): 64-lid chunk per XCD.
  const int lin = blockIdx.x + (blockIdx.y << 4);       // gridDim.x == 16
  const int lid = ((lin & 7) << 6) | (lin >> 3);        // bijective (512 % 8 == 0)
  const int bh = lid >> 4;
  const int b = bh >> 3, h = bh & 7;
  const int q0 = (lid & 15) << 7;

  // Q fragments: lane (ln,qd) holds Q[q = ..+ln][d = q8+e] -> B-operand of S^T
  bf16x8 aQ[2][2];
#pragma unroll
  for (int t = 0; t < 2; ++t) {
    const size_t rbase =
        ((size_t)(b * S1v + q0 + wv * 32 + t * 16 + ln)) * DM + h * HD;
    aQ[t][0] = *(const bf16x8*)(Qb + rbase + q8);
    aQ[t][1] = *(const bf16x8*)(Qb + rbase + 32 + q8);
  }

  // per-lane q-row coefficient (q = wv*32 + t*16 + ln)
  float acoef[2];
#pragma unroll
  for (int t = 0; t < 2; ++t)
    acoef[t] = (m1[b * S1v + q0 + wv * 32 + t * 16 + ln] == 0) ? 0.f : 1.f;

  float lrow[2] = {};
  f32x4 O[2][4] = {};

  for (int s0 = 0; s0 < S2v; s0 += 128) {
    __syncthreads();
#pragma unroll
    for (int i = 0; i < 4; ++i) {                   // K tile 128x64 (natural order)
      int cid = tid + i * 256;
      int r = cid >> 3, ch = (cid & 7) * 8;
      *(uint4*)&Ks[r][ch] =
          *(const uint4*)(Kb + ((size_t)(b * S2v + s0 + r)) * DM + h * HD + ch);
    }
#pragma unroll
    for (int i = 0; i < 4; ++i) {                   // V^T tile 64x128 (label order)
      int cid = tid + i * 256;
      int r = cid >> 4, ch = (cid & 15) * 8;
      *(uint4*)&Vts[r][ch] =
          *(const uint4*)(Kt + ((size_t)(bh * HD + r)) * (size_t)S2v + s0 + ch);
    }
    if (tid < 128) m2f[tid] = (m2[b * S2v + s0 + tid] != 0) ? 0.f : NEGB;
    __syncthreads();

    // S^T = K Q^T : lane (ln,qd) reg r of sc[t][j] = S[q=t*16+ln][k=16j+4qd+r]
    f32x4 sc[2][8];
#pragma unroll
    for (int j = 0; j < 8; ++j) {
      const bf16x8 k0f = *(const bf16x8*)&Ks[16 * j + ln][q8];
      const bf16x8 k1f = *(const bf16x8*)&Ks[16 * j + ln][32 + q8];
#pragma unroll
      for (int t = 0; t < 2; ++t) {
        f32x4 z = {};
        z = __builtin_amdgcn_mfma_f32_16x16x32_bf16(k0f, aQ[t][0], z, 0, 0, 0);
        sc[t][j] = __builtin_amdgcn_mfma_f32_16x16x32_bf16(k1f, aQ[t][1], z, 0, 0, 0);
      }
    }

    // p = exp2( a*(sc*SC_L2E + moff) + CBIAS ); mask at k = 16j+4qd+r
#pragma unroll
    for (int j = 0; j < 8; ++j) {
      const f32x4 mv = *(const f32x4*)&m2f[16 * j + 4 * qd];
#pragma unroll
      for (int t = 0; t < 2; ++t)
#pragma unroll
        for (int r = 0; r < 4; ++r) {
          const float e = fmaf(acoef[t], fmaf(sc[t][j][r], SC_L2E, mv[r]), CBIAS);
          const float p = __builtin_amdgcn_exp2f(e);
          lrow[t] += p;
          sc[t][j][r] = p;
        }
    }

    // O += P V : A-fragment is lane-local (label order), no LDS round-trip
#pragma unroll
    for (int kk = 0; kk < 4; ++kk) {
      bf16x8 aP[2];
#pragma unroll
      for (int t = 0; t < 2; ++t) {
        union { uint4 u; bf16x8 v; } cvt;
        cvt.u.x = __builtin_amdgcn_perm(asu(sc[t][kk][1]),     asu(sc[t][kk][0]),     0x07060302u);
        cvt.u.y = __builtin_amdgcn_perm(asu(sc[t][kk][3]),     asu(sc[t][kk][2]),     0x07060302u);
        cvt.u.z = __builtin_amdgcn_perm(asu(sc[t][kk + 4][1]), asu(sc[t][kk + 4][0]), 0x07060302u);
        cvt.u.w = __builtin_amdgcn_perm(asu(sc[t][kk + 4][3]), asu(sc[t][kk + 4][2]), 0x07060302u);
        aP[t] = cvt.v;
      }
#pragma unroll
      for (int jn = 0; jn < 4; ++jn) {
        const bf16x8 bV = *(const bf16x8*)&Vts[16 * jn + ln][kk * 32 + q8];
        O[0][jn] = __builtin_amdgcn_mfma_f32_16x16x32_bf16(aP[0], bV, O[0][jn], 0, 0, 0);
        O[1][jn] = __builtin_amdgcn_mfma_f32_16x16x32_bf16(aP[1], bV, O[1][jn], 0, 0, 0);
      }
    }
  }

  // row sums live per-lane for q = t*16+ln, spread over the 4 qd copies
  float inv[2];
#pragma unroll
  for (int t = 0; t < 2; ++t) {
    float l = lrow[t];
    l += __shfl_xor(l, 16, 64);
    l += __shfl_xor(l, 32, 64);
    inv[t] = l > 0.f ? 1.0f / l : 0.f;
  }
#pragma unroll
  for (int t = 0; t < 2; ++t)
#pragma unroll
    for (int r = 0; r < 4; ++r) {
      const float invr = __shfl(inv[t], 4 * qd + r, 64);  // sum for q-row 4qd+r
      const int m = q0 + wv * 32 + t * 16 + qd * 4 + r;
#pragma unroll
      for (int jn = 0; jn < 4; ++jn)
        attn[((size_t)(b * S1v + m)) * DM + h * HD + 16 * jn + ln] = O[t][jn][r] * invr;
    }
}

// ---------------- fused LN2(attn + LN1(attn + modal1)) ------------------------
__global__ __launch_bounds__(128)
void ln_fused(const float* __restrict__ attn, const float* __restrict__ modal1,
              const float* __restrict__ g1, const float* __restrict__ b1,
              const float* __restrict__ g2, const float* __restrict__ b2,
              float* __restrict__ out) {
  __shared__ float red[4];
  const int row = blockIdx.x, t = threadIdx.x;
  const size_t base = (size_t)row * DM + t * 4;
  const float4 a = *(const float4*)(attn + base);
  const float4 mo = *(const float4*)(modal1 + base);
  float av[4] = { a.x, a.y, a.z, a.w };
  float x[4] = { a.x + mo.x, a.y + mo.y, a.z + mo.z, a.w + mo.w };
  float s = 0.f, q = 0.f;
#pragma unroll
  for (int i = 0; i < 4; ++i) { s += x[i]; q += x[i] * x[i]; }
#pragma unroll
  for (int m = 1; m < 64; m <<= 1) { s += __shfl_xor(s, m, 64); q += __shfl_xor(q, m, 64); }
  if ((t & 63) == 0) { red[t >> 6] = s; red[2 + (t >> 6)] = q; }
  __syncthreads();
  s = red[0] + red[1]; q = red[2] + red[3];
  const float mu = s * (1.0f / DM);
  const float rinv = rsqrtf(q * (1.0f / DM) - mu * mu + 1e-5f);
  const int c = t * 4;
  const float4 G1 = *(const float4*)(g1 + c), B1 = *(const float4*)(b1 + c);
  const float gg1[4] = { G1.x, G1.y, G1.z, G1.w }, bb1[4] = { B1.x, B1.y, B1.z, B1.w };
  float y[4];
  float s2 = 0.f, q2 = 0.f;
#pragma unroll
  for (int i = 0; i < 4; ++i) {
    y[i] = av[i] + (x[i] - mu) * rinv * gg1[i] + bb1[i];
    s2 += y[i]; q2 += y[i] * y[i];
  }
#pragma unroll
  for (int m = 1; m < 64; m <<= 1) { s2 += __shfl_xor(s2, m, 64); q2 += __shfl_xor(q2, m, 64); }
  __syncthreads();
  if ((t & 63) == 0) { red[t >> 6] = s2; red[2 + (t >> 6)] = q2; }
  __syncthreads();
  s2 = red[0] + red[1]; q2 = red[2] + red[3];
  const float mu2 = s2 * (1.0f / DM);
  const float rinv2 = rsqrtf(q2 * (1.0f / DM) - mu2 * mu2 + 1e-5f);
  const float4 G2 = *(const float4*)(g2 + c), B2 = *(const float4*)(b2 + c);
  float4 o;
  o.x = (y[0] - mu2) * rinv2 * G2.x + B2.x;
  o.y = (y[1] - mu2) * rinv2 * G2.y + B2.y;
  o.z = (y[2] - mu2) * rinv2 * G2.z + B2.z;
  o.w = (y[3] - mu2) * rinv2 * G2.w + B2.w;
  *(float4*)(out + base) = o;
}

extern "C" void kernel_launch(void* const* d_in, const int* in_sizes, int n_in,
                              void* d_out, int out_size, void* d_ws, size_t ws_size,
                              hipStream_t stream) {
  const float* modal1 = (const float*)d_in[0];
  const float* modal2 = (const float*)d_in[1];
  const int*   m1     = (const int*)d_in[2];
  const int*   m2     = (const int*)d_in[3];
  const float* Wq     = (const float*)d_in[4];
  const float* bq     = (const float*)d_in[5];
  const float* Wkv    = (const float*)d_in[6];
  const float* bkv    = (const float*)d_in[7];
  const float* g1     = (const float*)d_in[8];
  const float* b1     = (const float*)d_in[9];
  // d_in[10..13] = FFN weights -> output discarded by the reference; skipped.
  const float* g2     = (const float*)d_in[14];
  const float* b2     = (const float*)d_in[15];
  float* out = (float*)d_out;

  char* ws = (char*)d_ws;
  unsigned short* q_bf  = (unsigned short*)(ws);                 //  8 MB
  unsigned short* k_bf  = (unsigned short*)(ws + 8388608);       //  8 MB
  unsigned short* kt_bf = (unsigned short*)(ws + 16777216);      //  8 MB
  unsigned short* wqt   = (unsigned short*)(ws + 25165824);      // 512 KB
  unsigned short* wkt   = (unsigned short*)(ws + 25690112);      // 512 KB
  float*          attn  = (float*)(ws + 26214400);               // 16 MB

  dim3 tb(32, 8);
  wtrans<<<dim3(16, 16), tb, 0, stream>>>(Wq, wqt);
  wtrans<<<dim3(16, 16), tb, 0, stream>>>(Wkv, wkt);
  proj_gemm<<<dim3(64, 4), 256, 0, stream>>>(modal1, wqt, bq, q_bf);
  proj_gemm<<<dim3(64, 4), 256, 0, stream>>>(modal2, wkt, bkv, k_bf);
  ktrans<<<dim3(16, 32), 256, 0, stream>>>(k_bf, kt_bf);
  flash_attn<<<dim3(16, 32), 256, 0, stream>>>(q_bf, k_bf, kt_bf, m1, m2, attn);
  ln_fused<<<dim3(8192), 128, 0, stream>>>(attn, modal1, g1, b1, g2, b2, out);
}

// Round 6
// 183.469 us; speedup vs baseline: 1.3311x; 1.0982x over previous
//
#include <hip/hip_runtime.h>
#include <hip/hip_bf16.h>

#define BSZ 4
#define S1v 2048
#define S2v 2048
#define DM 512
#define NH 8
#define HD 64
#define SCALE 0.044194173824159216f
#define L2E 1.4426950408889634f
#define SC_L2E (0.044194173824159216f * 1.4426950408889634f)
#define CBIAS 0.0028152f   /* log2(1+2^-9): centers truncating bf16 pack */
#define NEGB (-1e30f)

typedef __bf16 bf16x8 __attribute__((ext_vector_type(8)));
typedef float f32x4 __attribute__((ext_vector_type(4)));

__device__ __forceinline__ unsigned short f2bf(float f) {
  union { float f; unsigned u; } v; v.f = f;
  unsigned r = v.u + 0x7FFFu + ((v.u >> 16) & 1u);
  return (unsigned short)(r >> 16);
}
__device__ __forceinline__ unsigned asu(float f) {
  union { float f; unsigned u; } v; v.f = f; return v.u;
}

// ------------- weight transpose + cast, both weights in one launch ------------
__global__ __launch_bounds__(256)
void wtrans(const float* __restrict__ W0, const float* __restrict__ W1,
            unsigned short* __restrict__ T0, unsigned short* __restrict__ T1) {
  __shared__ float tile[32][33];
  const float* W = blockIdx.z ? W1 : W0;
  unsigned short* Wt = blockIdx.z ? T1 : T0;
  const int tx = threadIdx.x, ty = threadIdx.y;     // block (32,8)
  const int n0 = blockIdx.x * 32, k0 = blockIdx.y * 32;
#pragma unroll
  for (int i = 0; i < 32; i += 8)
    tile[ty + i][tx] = W[(size_t)(k0 + ty + i) * DM + n0 + tx];
  __syncthreads();
#pragma unroll
  for (int i = 0; i < 32; i += 8)
    Wt[(size_t)(n0 + ty + i) * DM + k0 + tx] = f2bf(tile[tx][ty + i]);
}

// ---------------- projection GEMM, BOTH projections in one launch --------------
// grid (64,4,2): z=0 -> Q = modal1@Wq+bq, z=1 -> KV = modal2@Wkv+bkv.
// 512 blocks = 2 blocks/CU (was 2 serial launches at 1 block/CU = 1 wave/SIMD):
// doubles wave-level latency hiding for the projection phase + saves a launch.
__global__ __launch_bounds__(256)
void proj_gemm(const float* __restrict__ X0, const float* __restrict__ X1,
               const unsigned short* __restrict__ Wt0, const unsigned short* __restrict__ Wt1,
               const float* __restrict__ bias0, const float* __restrict__ bias1,
               unsigned short* __restrict__ Y0, unsigned short* __restrict__ Y1) {
  __shared__ unsigned short Xs[128][72];
  __shared__ unsigned short Ws[128][72];
  const float* X = blockIdx.z ? X1 : X0;
  const unsigned short* Wt = blockIdx.z ? Wt1 : Wt0;
  const float* bias = blockIdx.z ? bias1 : bias0;
  unsigned short* Y = blockIdx.z ? Y1 : Y0;
  const int tid = threadIdx.x;
  const int wv = tid >> 6, lane = tid & 63;
  const int ln = lane & 15, qd = lane >> 4, q8 = qd * 8;
  const int wm = (wv >> 1) * 64, wn = (wv & 1) * 64;
  const int m0 = blockIdx.x * 128, n0 = blockIdx.y * 128;
  f32x4 acc[4][4] = {};
  for (int k0 = 0; k0 < DM; k0 += 64) {
    __syncthreads();
#pragma unroll
    for (int i = 0; i < 8; ++i) {                   // X tile 128x64 f32 -> bf16
      int cid = tid + i * 256;
      int r = cid >> 4, c4 = (cid & 15) * 4;
      const float4 v = *(const float4*)(X + (size_t)(m0 + r) * DM + k0 + c4);
      ushort4 bv;
      bv.x = f2bf(v.x); bv.y = f2bf(v.y); bv.z = f2bf(v.z); bv.w = f2bf(v.w);
      *(ushort4*)&Xs[r][c4] = bv;
    }
#pragma unroll
    for (int i = 0; i < 4; ++i) {                   // Wt tile 128x64 bf16 copy
      int cid = tid + i * 256;
      int r = cid >> 3, ch = (cid & 7) * 8;
      *(uint4*)&Ws[r][ch] = *(const uint4*)(Wt + (size_t)(n0 + r) * DM + k0 + ch);
    }
    __syncthreads();
#pragma unroll
    for (int kk = 0; kk < 2; ++kk) {
      bf16x8 aF[4], bF[4];
#pragma unroll
      for (int i = 0; i < 4; ++i)
        aF[i] = *(const bf16x8*)&Xs[wm + 16 * i + ln][kk * 32 + q8];
#pragma unroll
      for (int j = 0; j < 4; ++j)
        bF[j] = *(const bf16x8*)&Ws[wn + 16 * j + ln][kk * 32 + q8];
#pragma unroll
      for (int i = 0; i < 4; ++i)
#pragma unroll
        for (int j = 0; j < 4; ++j)
          acc[i][j] = __builtin_amdgcn_mfma_f32_16x16x32_bf16(aF[i], bF[j], acc[i][j], 0, 0, 0);
    }
  }
#pragma unroll
  for (int i = 0; i < 4; ++i)
#pragma unroll
    for (int j = 0; j < 4; ++j) {
      const int n = n0 + wn + 16 * j + ln;
      const float bb = bias[n];
#pragma unroll
      for (int r = 0; r < 4; ++r) {
        const int m = m0 + wm + 16 * i + qd * 4 + r;
        Y[(size_t)m * DM + n] = f2bf(acc[i][j][r] + bb);
      }
    }
}

// ---------------- K^T builder with PV-label permutation baked in ---------------
// flash_attn's swapped QK^T leaves lane (ln,qd) holding P[q][k = 16j+4qd+r].
// Its PV A-fragment slot (kk, e) corresponds to label c = kk*32 + qd*8 + e.
// V must be staged with its rows in label order: col c holds original row
// u(c) = 16*(c>>5) + 4*((c>>3)&3) + 64*((c>>2)&1) + (c&3).
// For c = a*8 + w:  u = 16*(a>>2) + 4*(a&3) + 64*(w>>2) + (w&3).
__global__ __launch_bounds__(256)
void ktrans(const unsigned short* __restrict__ K, unsigned short* __restrict__ Kt) {
  __shared__ unsigned short T[128][72];
  const int tid = threadIdx.x;
  const int bh = blockIdx.y, b = bh >> 3, h = bh & 7;
  const int s0 = blockIdx.x * 128;
#pragma unroll
  for (int i = 0; i < 4; ++i) {                     // load tile [128 s][64 d]
    int cid = tid + i * 256;
    int r = cid >> 3, ch = (cid & 7) * 8;
    *(uint4*)&T[r][ch] =
        *(const uint4*)(K + (size_t)(b * S2v + s0 + r) * DM + h * HD + ch);
  }
  __syncthreads();
#pragma unroll
  for (int i = 0; i < 4; ++i) {                     // write [64 d][128 c]
    int cid = tid + i * 256;
    int d = cid >> 4, a = cid & 15;
    const int base = 16 * (a >> 2) + 4 * (a & 3);
    ushort4 v0, v1;
    v0.x = T[base + 0][d]; v0.y = T[base + 1][d];
    v0.z = T[base + 2][d]; v0.w = T[base + 3][d];
    v1.x = T[base + 64][d]; v1.y = T[base + 65][d];
    v1.z = T[base + 66][d]; v1.w = T[base + 67][d];
    unsigned short* o = Kt + ((size_t)(bh * HD + d)) * (size_t)S2v + s0 + a * 8;
    *(ushort4*)o = v0;
    *(ushort4*)(o + 4) = v1;
  }
}

// ---------------- flash attention (V = K), masked, static softmax --------------
// grid (S1/128, BSZ*NH), block 256: 4 waves x 32 Q-rows (2 subtiles of 16).
// Round-6: R5 (swapped QK^T, no P round-trip) + T14 async-stage double-buffer:
// next tile's K/Vt/m2 global loads issue BEFORE compute (latency hides under
// QK+softmax+PV), ds_write into the alternate LDS buffer AFTER compute, one
// barrier per iter.  The staging drain leaves the per-iteration critical path.
// Single register set (33 VGPR), launch_bounds(256,2) -> VGPR cap 256, no
// spill (R1 lesson: double-set prefetch under a tight cap spilled to scratch;
// tripwire = WRITE_SIZE must stay ~16.4MB).  Grid caps occupancy at 2
// blocks/CU, so the doubled LDS (72.9KB) costs nothing.
__global__ __launch_bounds__(256, 2)
void flash_attn(const unsigned short* __restrict__ Qb, const unsigned short* __restrict__ Kb,
                const unsigned short* __restrict__ Kt, const int* __restrict__ m1,
                const int* __restrict__ m2, float* __restrict__ attn) {
  __shared__ unsigned short Ks[2][128][72];
  __shared__ unsigned short Vts[2][64][136];
  __shared__ float m2f[2][128];

  const int tid = threadIdx.x;
  const int wv = tid >> 6, lane = tid & 63;
  const int ln = lane & 15, qd = lane >> 4, q8 = qd * 8;
  // XCD swizzle (kept: FETCH 70->12.4MB): 64-lid chunk per XCD.
  const int lin = blockIdx.x + (blockIdx.y << 4);       // gridDim.x == 16
  const int lid = ((lin & 7) << 6) | (lin >> 3);        // bijective (512 % 8 == 0)
  const int bh = lid >> 4;
  const int b = bh >> 3, h = bh & 7;
  const int q0 = (lid & 15) << 7;

  // staging coordinates (constant per thread)
  const int rK = tid >> 3, cK = (tid & 7) * 8;          // K tile: 4 x uint4
  const int rV = tid >> 4, cV = (tid & 15) * 8;         // Vt tile: 4 x uint4
  const unsigned short* kbase = Kb + ((size_t)(b * S2v) + rK) * DM + h * HD + cK;
  const unsigned short* vbase = Kt + ((size_t)(bh * HD + rV)) * (size_t)S2v + cV;

  // Q fragments: lane (ln,qd) holds Q[q = ..+ln][d = q8+e] -> B-operand of S^T
  bf16x8 aQ[2][2];
#pragma unroll
  for (int t = 0; t < 2; ++t) {
    const size_t rbase =
        ((size_t)(b * S1v + q0 + wv * 32 + t * 16 + ln)) * DM + h * HD;
    aQ[t][0] = *(const bf16x8*)(Qb + rbase + q8);
    aQ[t][1] = *(const bf16x8*)(Qb + rbase + 32 + q8);
  }

  float acoef[2];
#pragma unroll
  for (int t = 0; t < 2; ++t)
    acoef[t] = (m1[b * S1v + q0 + wv * 32 + t * 16 + ln] == 0) ? 0.f : 1.f;

  float lrow[2] = {};
  f32x4 O[2][4] = {};

  // prologue: stage tile 0 into buffer 0
#pragma unroll
  for (int i = 0; i < 4; ++i)
    *(uint4*)&Ks[0][rK + i * 32][cK] = *(const uint4*)(kbase + (size_t)(i * 32) * DM);
#pragma unroll
  for (int i = 0; i < 4; ++i)
    *(uint4*)&Vts[0][rV + i * 16][cV] =
        *(const uint4*)(vbase + (size_t)(i * 16) * (size_t)S2v);
  if (tid < 128) m2f[0][tid] = (m2[b * S2v + tid] != 0) ? 0.f : NEGB;
  __syncthreads();

  for (int it = 0; it < 16; ++it) {
    const int cur = it & 1;
    const bool pf = (it != 15);

    // T14 issue-early: next tile's global loads, consumed after compute
    uint4 nk[4], nv[4]; float nm = 0.f;
    if (pf) {
      const int sn = (it + 1) << 7;
#pragma unroll
      for (int i = 0; i < 4; ++i)
        nk[i] = *(const uint4*)(kbase + ((size_t)sn + (size_t)(i * 32)) * DM);
#pragma unroll
      for (int i = 0; i < 4; ++i)
        nv[i] = *(const uint4*)(vbase + sn + (size_t)(i * 16) * (size_t)S2v);
      if (tid < 128) nm = (m2[b * S2v + sn + tid] != 0) ? 0.f : NEGB;
    }

    // S^T = K Q^T : lane (ln,qd) reg r of sc[t][j] = S[q=t*16+ln][k=16j+4qd+r]
    f32x4 sc[2][8];
#pragma unroll
    for (int j = 0; j < 8; ++j) {
      const bf16x8 k0f = *(const bf16x8*)&Ks[cur][16 * j + ln][q8];
      const bf16x8 k1f = *(const bf16x8*)&Ks[cur][16 * j + ln][32 + q8];
#pragma unroll
      for (int t = 0; t < 2; ++t) {
        f32x4 z = {};
        z = __builtin_amdgcn_mfma_f32_16x16x32_bf16(k0f, aQ[t][0], z, 0, 0, 0);
        sc[t][j] = __builtin_amdgcn_mfma_f32_16x16x32_bf16(k1f, aQ[t][1], z, 0, 0, 0);
      }
    }

    // p = exp2( a*(sc*SC_L2E + moff) + CBIAS ); mask at k = 16j+4qd+r
#pragma unroll
    for (int j = 0; j < 8; ++j) {
      const f32x4 mv = *(const f32x4*)&m2f[cur][16 * j + 4 * qd];
#pragma unroll
      for (int t = 0; t < 2; ++t)
#pragma unroll
        for (int r = 0; r < 4; ++r) {
          const float e = fmaf(acoef[t], fmaf(sc[t][j][r], SC_L2E, mv[r]), CBIAS);
          const float p = __builtin_amdgcn_exp2f(e);
          lrow[t] += p;
          sc[t][j][r] = p;
        }
    }

    // O += P V : A-fragment is lane-local (label order), no LDS round-trip
#pragma unroll
    for (int kk = 0; kk < 4; ++kk) {
      bf16x8 aP[2];
#pragma unroll
      for (int t = 0; t < 2; ++t) {
        union { uint4 u; bf16x8 v; } cvt;
        cvt.u.x = __builtin_amdgcn_perm(asu(sc[t][kk][1]),     asu(sc[t][kk][0]),     0x07060302u);
        cvt.u.y = __builtin_amdgcn_perm(asu(sc[t][kk][3]),     asu(sc[t][kk][2]),     0x07060302u);
        cvt.u.z = __builtin_amdgcn_perm(asu(sc[t][kk + 4][1]), asu(sc[t][kk + 4][0]), 0x07060302u);
        cvt.u.w = __builtin_amdgcn_perm(asu(sc[t][kk + 4][3]), asu(sc[t][kk + 4][2]), 0x07060302u);
        aP[t] = cvt.v;
      }
#pragma unroll
      for (int jn = 0; jn < 4; ++jn) {
        const bf16x8 bV = *(const bf16x8*)&Vts[cur][16 * jn + ln][kk * 32 + q8];
        O[0][jn] = __builtin_amdgcn_mfma_f32_16x16x32_bf16(aP[0], bV, O[0][jn], 0, 0, 0);
        O[1][jn] = __builtin_amdgcn_mfma_f32_16x16x32_bf16(aP[1], bV, O[1][jn], 0, 0, 0);
      }
    }

    // T14 write-late: drain (compiler inserts vmcnt) + stage into alt buffer
    if (pf) {
#pragma unroll
      for (int i = 0; i < 4; ++i) *(uint4*)&Ks[cur ^ 1][rK + i * 32][cK] = nk[i];
#pragma unroll
      for (int i = 0; i < 4; ++i) *(uint4*)&Vts[cur ^ 1][rV + i * 16][cV] = nv[i];
      if (tid < 128) m2f[cur ^ 1][tid] = nm;
      __syncthreads();
    }
  }

  // row sums live per-lane for q = t*16+ln, spread over the 4 qd copies
  float inv[2];
#pragma unroll
  for (int t = 0; t < 2; ++t) {
    float l = lrow[t];
    l += __shfl_xor(l, 16, 64);
    l += __shfl_xor(l, 32, 64);
    inv[t] = l > 0.f ? 1.0f / l : 0.f;
  }
#pragma unroll
  for (int t = 0; t < 2; ++t)
#pragma unroll
    for (int r = 0; r < 4; ++r) {
      const float invr = __shfl(inv[t], 4 * qd + r, 64);  // sum for q-row 4qd+r
      const int m = q0 + wv * 32 + t * 16 + qd * 4 + r;
#pragma unroll
      for (int jn = 0; jn < 4; ++jn)
        attn[((size_t)(b * S1v + m)) * DM + h * HD + 16 * jn + ln] = O[t][jn][r] * invr;
    }
}

// ---------------- fused LN2(attn + LN1(attn + modal1)) ------------------------
__global__ __launch_bounds__(128)
void ln_fused(const float* __restrict__ attn, const float* __restrict__ modal1,
              const float* __restrict__ g1, const float* __restrict__ b1,
              const float* __restrict__ g2, const float* __restrict__ b2,
              float* __restrict__ out) {
  __shared__ float red[4];
  const int row = blockIdx.x, t = threadIdx.x;
  const size_t base = (size_t)row * DM + t * 4;
  const float4 a = *(const float4*)(attn + base);
  const float4 mo = *(const float4*)(modal1 + base);
  float av[4] = { a.x, a.y, a.z, a.w };
  float x[4] = { a.x + mo.x, a.y + mo.y, a.z + mo.z, a.w + mo.w };
  float s = 0.f, q = 0.f;
#pragma unroll
  for (int i = 0; i < 4; ++i) { s += x[i]; q += x[i] * x[i]; }
#pragma unroll
  for (int m = 1; m < 64; m <<= 1) { s += __shfl_xor(s, m, 64); q += __shfl_xor(q, m, 64); }
  if ((t & 63) == 0) { red[t >> 6] = s; red[2 + (t >> 6)] = q; }
  __syncthreads();
  s = red[0] + red[1]; q = red[2] + red[3];
  const float mu = s * (1.0f / DM);
  const float rinv = rsqrtf(q * (1.0f / DM) - mu * mu + 1e-5f);
  const int c = t * 4;
  const float4 G1 = *(const float4*)(g1 + c), B1 = *(const float4*)(b1 + c);
  const float gg1[4] = { G1.x, G1.y, G1.z, G1.w }, bb1[4] = { B1.x, B1.y, B1.z, B1.w };
  float y[4];
  float s2 = 0.f, q2 = 0.f;
#pragma unroll
  for (int i = 0; i < 4; ++i) {
    y[i] = av[i] + (x[i] - mu) * rinv * gg1[i] + bb1[i];
    s2 += y[i]; q2 += y[i] * y[i];
  }
#pragma unroll
  for (int m = 1; m < 64; m <<= 1) { s2 += __shfl_xor(s2, m, 64); q2 += __shfl_xor(q2, m, 64); }
  __syncthreads();
  if ((t & 63) == 0) { red[t >> 6] = s2; red[2 + (t >> 6)] = q2; }
  __syncthreads();
  s2 = red[0] + red[1]; q2 = red[2] + red[3];
  const float mu2 = s2 * (1.0f / DM);
  const float rinv2 = rsqrtf(q2 * (1.0f / DM) - mu2 * mu2 + 1e-5f);
  const float4 G2 = *(const float4*)(g2 + c), B2 = *(const float4*)(b2 + c);
  float4 o;
  o.x = (y[0] - mu2) * rinv2 * G2.x + B2.x;
  o.y = (y[1] - mu2) * rinv2 * G2.y + B2.y;
  o.z = (y[2] - mu2) * rinv2 * G2.z + B2.z;
  o.w = (y[3] - mu2) * rinv2 * G2.w + B2.w;
  *(float4*)(out + base) = o;
}

extern "C" void kernel_launch(void* const* d_in, const int* in_sizes, int n_in,
                              void* d_out, int out_size, void* d_ws, size_t ws_size,
                              hipStream_t stream) {
  const float* modal1 = (const float*)d_in[0];
  const float* modal2 = (const float*)d_in[1];
  const int*   m1     = (const int*)d_in[2];
  const int*   m2     = (const int*)d_in[3];
  const float* Wq     = (const float*)d_in[4];
  const float* bq     = (const float*)d_in[5];
  const float* Wkv    = (const float*)d_in[6];
  const float* bkv    = (const float*)d_in[7];
  const float* g1     = (const float*)d_in[8];
  const float* b1     = (const float*)d_in[9];
  // d_in[10..13] = FFN weights -> output discarded by the reference; skipped.
  const float* g2     = (const float*)d_in[14];
  const float* b2     = (const float*)d_in[15];
  float* out = (float*)d_out;

  char* ws = (char*)d_ws;
  unsigned short* q_bf  = (unsigned short*)(ws);                 //  8 MB
  unsigned short* k_bf  = (unsigned short*)(ws + 8388608);       //  8 MB
  unsigned short* kt_bf = (unsigned short*)(ws + 16777216);      //  8 MB
  unsigned short* wqt   = (unsigned short*)(ws + 25165824);      // 512 KB
  unsigned short* wkt   = (unsigned short*)(ws + 25690112);      // 512 KB
  float*          attn  = (float*)(ws + 26214400);               // 16 MB

  dim3 tb(32, 8);
  wtrans<<<dim3(16, 16, 2), tb, 0, stream>>>(Wq, Wkv, wqt, wkt);
  proj_gemm<<<dim3(64, 4, 2), 256, 0, stream>>>(modal1, modal2, wqt, wkt,
                                                bq, bkv, q_bf, k_bf);
  ktrans<<<dim3(16, 32), 256, 0, stream>>>(k_bf, kt_bf);
  flash_attn<<<dim3(16, 32), 256, 0, stream>>>(q_bf, k_bf, kt_bf, m1, m2, attn);
  ln_fused<<<dim3(8192), 128, 0, stream>>>(attn, modal1, g1, b1, g2, b2, out);
}

// Round 7
// 183.064 us; speedup vs baseline: 1.3341x; 1.0022x over previous
//
#include <hip/hip_runtime.h>
#include <hip/hip_bf16.h>

#define BSZ 4
#define S1v 2048
#define S2v 2048
#define DM 512
#define NH 8
#define HD 64
#define SCALE 0.044194173824159216f
#define L2E 1.4426950408889634f
#define SC_L2E (0.044194173824159216f * 1.4426950408889634f)
#define CBIAS 0.0028152f   /* log2(1+2^-9): centers truncating bf16 pack */
#define NEGB (-1e30f)

typedef __bf16 bf16x8 __attribute__((ext_vector_type(8)));
typedef float f32x4 __attribute__((ext_vector_type(4)));

__device__ __forceinline__ unsigned short f2bf(float f) {
  union { float f; unsigned u; } v; v.f = f;
  unsigned r = v.u + 0x7FFFu + ((v.u >> 16) & 1u);
  return (unsigned short)(r >> 16);
}
__device__ __forceinline__ unsigned asu(float f) {
  union { float f; unsigned u; } v; v.f = f; return v.u;
}

// ------------- weight transpose + cast, both weights in one launch ------------
__global__ __launch_bounds__(256)
void wtrans(const float* __restrict__ W0, const float* __restrict__ W1,
            unsigned short* __restrict__ T0, unsigned short* __restrict__ T1) {
  __shared__ float tile[32][33];
  const float* W = blockIdx.z ? W1 : W0;
  unsigned short* Wt = blockIdx.z ? T1 : T0;
  const int tx = threadIdx.x, ty = threadIdx.y;     // block (32,8)
  const int n0 = blockIdx.x * 32, k0 = blockIdx.y * 32;
#pragma unroll
  for (int i = 0; i < 32; i += 8)
    tile[ty + i][tx] = W[(size_t)(k0 + ty + i) * DM + n0 + tx];
  __syncthreads();
#pragma unroll
  for (int i = 0; i < 32; i += 8)
    Wt[(size_t)(n0 + ty + i) * DM + k0 + tx] = f2bf(tile[tx][ty + i]);
}

// ---------------- projection GEMM, BOTH projections in one launch --------------
// grid (64,4,2): z=0 -> Q = modal1@Wq+bq, z=1 -> KV = modal2@Wkv+bkv.
// Round-7: ktrans FUSED into the z=1 epilogue.  A KV block's output tile is
// exactly one 128-s block x 2 heads -- the granularity ktrans retransposed
// after an HBM round-trip.  Here the bf16 Y values are also staged into LDS
// (T2) and written to Kt in label order (identical u(c) permutation, identical
// rounded values -> bit-identical kt_bf).  Removes one kernel launch + gap +
// ktrans's 8.4MB k_bf re-read.  LDS 71.7KB still fits 2 blocks/CU (grid-capped).
__global__ __launch_bounds__(256)
void proj_gemm(const float* __restrict__ X0, const float* __restrict__ X1,
               const unsigned short* __restrict__ Wt0, const unsigned short* __restrict__ Wt1,
               const float* __restrict__ bias0, const float* __restrict__ bias1,
               unsigned short* __restrict__ Y0, unsigned short* __restrict__ Y1,
               unsigned short* __restrict__ Kt) {
  __shared__ unsigned short Xs[128][72];
  __shared__ unsigned short Ws[128][72];
  __shared__ unsigned short T2[128][136];           // z=1 transpose stage
  const float* X = blockIdx.z ? X1 : X0;
  const unsigned short* Wt = blockIdx.z ? Wt1 : Wt0;
  const float* bias = blockIdx.z ? bias1 : bias0;
  unsigned short* Y = blockIdx.z ? Y1 : Y0;
  const int tid = threadIdx.x;
  const int wv = tid >> 6, lane = tid & 63;
  const int ln = lane & 15, qd = lane >> 4, q8 = qd * 8;
  const int wm = (wv >> 1) * 64, wn = (wv & 1) * 64;
  const int m0 = blockIdx.x * 128, n0 = blockIdx.y * 128;
  f32x4 acc[4][4] = {};
  for (int k0 = 0; k0 < DM; k0 += 64) {
    __syncthreads();
#pragma unroll
    for (int i = 0; i < 8; ++i) {                   // X tile 128x64 f32 -> bf16
      int cid = tid + i * 256;
      int r = cid >> 4, c4 = (cid & 15) * 4;
      const float4 v = *(const float4*)(X + (size_t)(m0 + r) * DM + k0 + c4);
      ushort4 bv;
      bv.x = f2bf(v.x); bv.y = f2bf(v.y); bv.z = f2bf(v.z); bv.w = f2bf(v.w);
      *(ushort4*)&Xs[r][c4] = bv;
    }
#pragma unroll
    for (int i = 0; i < 4; ++i) {                   // Wt tile 128x64 bf16 copy
      int cid = tid + i * 256;
      int r = cid >> 3, ch = (cid & 7) * 8;
      *(uint4*)&Ws[r][ch] = *(const uint4*)(Wt + (size_t)(n0 + r) * DM + k0 + ch);
    }
    __syncthreads();
#pragma unroll
    for (int kk = 0; kk < 2; ++kk) {
      bf16x8 aF[4], bF[4];
#pragma unroll
      for (int i = 0; i < 4; ++i)
        aF[i] = *(const bf16x8*)&Xs[wm + 16 * i + ln][kk * 32 + q8];
#pragma unroll
      for (int j = 0; j < 4; ++j)
        bF[j] = *(const bf16x8*)&Ws[wn + 16 * j + ln][kk * 32 + q8];
#pragma unroll
      for (int i = 0; i < 4; ++i)
#pragma unroll
        for (int j = 0; j < 4; ++j)
          acc[i][j] = __builtin_amdgcn_mfma_f32_16x16x32_bf16(aF[i], bF[j], acc[i][j], 0, 0, 0);
    }
  }
#pragma unroll
  for (int i = 0; i < 4; ++i)
#pragma unroll
    for (int j = 0; j < 4; ++j) {
      const int n = n0 + wn + 16 * j + ln;
      const float bb = bias[n];
#pragma unroll
      for (int r = 0; r < 4; ++r) {
        const int m = m0 + wm + 16 * i + qd * 4 + r;
        const unsigned short yb = f2bf(acc[i][j][r] + bb);
        Y[(size_t)m * DM + n] = yb;
        if (blockIdx.z) T2[wm + 16 * i + qd * 4 + r][wn + 16 * j + ln] = yb;
      }
    }
  if (blockIdx.z) {                                 // fused ktrans (KV only)
    __syncthreads();
    const int b = m0 >> 11, s0 = m0 & 2047;         // batch, 128-aligned s-block
    const int h0 = n0 >> 6;                         // first of 2 heads in tile
#pragma unroll
    for (int i = 0; i < 8; ++i) {
      const int cid = tid + i * 256;                // 2048 uint4-pair slots
      const int nl = cid >> 4, a = cid & 15;
      const int hh = h0 + (nl >> 6), d = nl & 63;
      const int base = 16 * (a >> 2) + 4 * (a & 3);
      ushort4 v0, v1;
      v0.x = T2[base + 0][nl]; v0.y = T2[base + 1][nl];
      v0.z = T2[base + 2][nl]; v0.w = T2[base + 3][nl];
      v1.x = T2[base + 64][nl]; v1.y = T2[base + 65][nl];
      v1.z = T2[base + 66][nl]; v1.w = T2[base + 67][nl];
      unsigned short* o =
          Kt + ((size_t)((b * 8 + hh) * HD + d)) * (size_t)S2v + s0 + a * 8;
      *(ushort4*)o = v0;
      *(ushort4*)(o + 4) = v1;
    }
  }
}

// ---------------- flash attention (V = K), masked, static softmax --------------
// grid (S1/128, BSZ*NH), block 256: 4 waves x 32 Q-rows (2 subtiles of 16).
// R5 swapped QK^T (no P round-trip) + R6 T14 async-stage double-buffer.
// Unchanged from the verified R6 kernel (54.5us, WRITE at 16.4MB ideal).
__global__ __launch_bounds__(256, 2)
void flash_attn(const unsigned short* __restrict__ Qb, const unsigned short* __restrict__ Kb,
                const unsigned short* __restrict__ Kt, const int* __restrict__ m1,
                const int* __restrict__ m2, float* __restrict__ attn) {
  __shared__ unsigned short Ks[2][128][72];
  __shared__ unsigned short Vts[2][64][136];
  __shared__ float m2f[2][128];

  const int tid = threadIdx.x;
  const int wv = tid >> 6, lane = tid & 63;
  const int ln = lane & 15, qd = lane >> 4, q8 = qd * 8;
  // XCD swizzle (kept: FETCH 70->12.4MB): 64-lid chunk per XCD.
  const int lin = blockIdx.x + (blockIdx.y << 4);       // gridDim.x == 16
  const int lid = ((lin & 7) << 6) | (lin >> 3);        // bijective (512 % 8 == 0)
  const int bh = lid >> 4;
  const int b = bh >> 3, h = bh & 7;
  const int q0 = (lid & 15) << 7;

  // staging coordinates (constant per thread)
  const int rK = tid >> 3, cK = (tid & 7) * 8;          // K tile: 4 x uint4
  const int rV = tid >> 4, cV = (tid & 15) * 8;         // Vt tile: 4 x uint4
  const unsigned short* kbase = Kb + ((size_t)(b * S2v) + rK) * DM + h * HD + cK;
  const unsigned short* vbase = Kt + ((size_t)(bh * HD + rV)) * (size_t)S2v + cV;

  // Q fragments: lane (ln,qd) holds Q[q = ..+ln][d = q8+e] -> B-operand of S^T
  bf16x8 aQ[2][2];
#pragma unroll
  for (int t = 0; t < 2; ++t) {
    const size_t rbase =
        ((size_t)(b * S1v + q0 + wv * 32 + t * 16 + ln)) * DM + h * HD;
    aQ[t][0] = *(const bf16x8*)(Qb + rbase + q8);
    aQ[t][1] = *(const bf16x8*)(Qb + rbase + 32 + q8);
  }

  float acoef[2];
#pragma unroll
  for (int t = 0; t < 2; ++t)
    acoef[t] = (m1[b * S1v + q0 + wv * 32 + t * 16 + ln] == 0) ? 0.f : 1.f;

  float lrow[2] = {};
  f32x4 O[2][4] = {};

  // prologue: stage tile 0 into buffer 0
#pragma unroll
  for (int i = 0; i < 4; ++i)
    *(uint4*)&Ks[0][rK + i * 32][cK] = *(const uint4*)(kbase + (size_t)(i * 32) * DM);
#pragma unroll
  for (int i = 0; i < 4; ++i)
    *(uint4*)&Vts[0][rV + i * 16][cV] =
        *(const uint4*)(vbase + (size_t)(i * 16) * (size_t)S2v);
  if (tid < 128) m2f[0][tid] = (m2[b * S2v + tid] != 0) ? 0.f : NEGB;
  __syncthreads();

  for (int it = 0; it < 16; ++it) {
    const int cur = it & 1;
    const bool pf = (it != 15);

    // T14 issue-early: next tile's global loads, consumed after compute
    uint4 nk[4], nv[4]; float nm = 0.f;
    if (pf) {
      const int sn = (it + 1) << 7;
#pragma unroll
      for (int i = 0; i < 4; ++i)
        nk[i] = *(const uint4*)(kbase + ((size_t)sn + (size_t)(i * 32)) * DM);
#pragma unroll
      for (int i = 0; i < 4; ++i)
        nv[i] = *(const uint4*)(vbase + sn + (size_t)(i * 16) * (size_t)S2v);
      if (tid < 128) nm = (m2[b * S2v + sn + tid] != 0) ? 0.f : NEGB;
    }

    // S^T = K Q^T : lane (ln,qd) reg r of sc[t][j] = S[q=t*16+ln][k=16j+4qd+r]
    f32x4 sc[2][8];
#pragma unroll
    for (int j = 0; j < 8; ++j) {
      const bf16x8 k0f = *(const bf16x8*)&Ks[cur][16 * j + ln][q8];
      const bf16x8 k1f = *(const bf16x8*)&Ks[cur][16 * j + ln][32 + q8];
#pragma unroll
      for (int t = 0; t < 2; ++t) {
        f32x4 z = {};
        z = __builtin_amdgcn_mfma_f32_16x16x32_bf16(k0f, aQ[t][0], z, 0, 0, 0);
        sc[t][j] = __builtin_amdgcn_mfma_f32_16x16x32_bf16(k1f, aQ[t][1], z, 0, 0, 0);
      }
    }

    // p = exp2( a*(sc*SC_L2E + moff) + CBIAS ); mask at k = 16j+4qd+r
#pragma unroll
    for (int j = 0; j < 8; ++j) {
      const f32x4 mv = *(const f32x4*)&m2f[cur][16 * j + 4 * qd];
#pragma unroll
      for (int t = 0; t < 2; ++t)
#pragma unroll
        for (int r = 0; r < 4; ++r) {
          const float e = fmaf(acoef[t], fmaf(sc[t][j][r], SC_L2E, mv[r]), CBIAS);
          const float p = __builtin_amdgcn_exp2f(e);
          lrow[t] += p;
          sc[t][j][r] = p;
        }
    }

    // O += P V : A-fragment is lane-local (label order), no LDS round-trip
#pragma unroll
    for (int kk = 0; kk < 4; ++kk) {
      bf16x8 aP[2];
#pragma unroll
      for (int t = 0; t < 2; ++t) {
        union { uint4 u; bf16x8 v; } cvt;
        cvt.u.x = __builtin_amdgcn_perm(asu(sc[t][kk][1]),     asu(sc[t][kk][0]),     0x07060302u);
        cvt.u.y = __builtin_amdgcn_perm(asu(sc[t][kk][3]),     asu(sc[t][kk][2]),     0x07060302u);
        cvt.u.z = __builtin_amdgcn_perm(asu(sc[t][kk + 4][1]), asu(sc[t][kk + 4][0]), 0x07060302u);
        cvt.u.w = __builtin_amdgcn_perm(asu(sc[t][kk + 4][3]), asu(sc[t][kk + 4][2]), 0x07060302u);
        aP[t] = cvt.v;
      }
#pragma unroll
      for (int jn = 0; jn < 4; ++jn) {
        const bf16x8 bV = *(const bf16x8*)&Vts[cur][16 * jn + ln][kk * 32 + q8];
        O[0][jn] = __builtin_amdgcn_mfma_f32_16x16x32_bf16(aP[0], bV, O[0][jn], 0, 0, 0);
        O[1][jn] = __builtin_amdgcn_mfma_f32_16x16x32_bf16(aP[1], bV, O[1][jn], 0, 0, 0);
      }
    }

    // T14 write-late: drain (compiler inserts vmcnt) + stage into alt buffer
    if (pf) {
#pragma unroll
      for (int i = 0; i < 4; ++i) *(uint4*)&Ks[cur ^ 1][rK + i * 32][cK] = nk[i];
#pragma unroll
      for (int i = 0; i < 4; ++i) *(uint4*)&Vts[cur ^ 1][rV + i * 16][cV] = nv[i];
      if (tid < 128) m2f[cur ^ 1][tid] = nm;
      __syncthreads();
    }
  }

  // row sums live per-lane for q = t*16+ln, spread over the 4 qd copies
  float inv[2];
#pragma unroll
  for (int t = 0; t < 2; ++t) {
    float l = lrow[t];
    l += __shfl_xor(l, 16, 64);
    l += __shfl_xor(l, 32, 64);
    inv[t] = l > 0.f ? 1.0f / l : 0.f;
  }
#pragma unroll
  for (int t = 0; t < 2; ++t)
#pragma unroll
    for (int r = 0; r < 4; ++r) {
      const float invr = __shfl(inv[t], 4 * qd + r, 64);  // sum for q-row 4qd+r
      const int m = q0 + wv * 32 + t * 16 + qd * 4 + r;
#pragma unroll
      for (int jn = 0; jn < 4; ++jn)
        attn[((size_t)(b * S1v + m)) * DM + h * HD + 16 * jn + ln] = O[t][jn][r] * invr;
    }
}

// ---------------- fused LN2(attn + LN1(attn + modal1)) ------------------------
__global__ __launch_bounds__(128)
void ln_fused(const float* __restrict__ attn, const float* __restrict__ modal1,
              const float* __restrict__ g1, const float* __restrict__ b1,
              const float* __restrict__ g2, const float* __restrict__ b2,
              float* __restrict__ out) {
  __shared__ float red[4];
  const int row = blockIdx.x, t = threadIdx.x;
  const size_t base = (size_t)row * DM + t * 4;
  const float4 a = *(const float4*)(attn + base);
  const float4 mo = *(const float4*)(modal1 + base);
  float av[4] = { a.x, a.y, a.z, a.w };
  float x[4] = { a.x + mo.x, a.y + mo.y, a.z + mo.z, a.w + mo.w };
  float s = 0.f, q = 0.f;
#pragma unroll
  for (int i = 0; i < 4; ++i) { s += x[i]; q += x[i] * x[i]; }
#pragma unroll
  for (int m = 1; m < 64; m <<= 1) { s += __shfl_xor(s, m, 64); q += __shfl_xor(q, m, 64); }
  if ((t & 63) == 0) { red[t >> 6] = s; red[2 + (t >> 6)] = q; }
  __syncthreads();
  s = red[0] + red[1]; q = red[2] + red[3];
  const float mu = s * (1.0f / DM);
  const float rinv = rsqrtf(q * (1.0f / DM) - mu * mu + 1e-5f);
  const int c = t * 4;
  const float4 G1 = *(const float4*)(g1 + c), B1 = *(const float4*)(b1 + c);
  const float gg1[4] = { G1.x, G1.y, G1.z, G1.w }, bb1[4] = { B1.x, B1.y, B1.z, B1.w };
  float y[4];
  float s2 = 0.f, q2 = 0.f;
#pragma unroll
  for (int i = 0; i < 4; ++i) {
    y[i] = av[i] + (x[i] - mu) * rinv * gg1[i] + bb1[i];
    s2 += y[i]; q2 += y[i] * y[i];
  }
#pragma unroll
  for (int m = 1; m < 64; m <<= 1) { s2 += __shfl_xor(s2, m, 64); q2 += __shfl_xor(q2, m, 64); }
  __syncthreads();
  if ((t & 63) == 0) { red[t >> 6] = s2; red[2 + (t >> 6)] = q2; }
  __syncthreads();
  s2 = red[0] + red[1]; q2 = red[2] + red[3];
  const float mu2 = s2 * (1.0f / DM);
  const float rinv2 = rsqrtf(q2 * (1.0f / DM) - mu2 * mu2 + 1e-5f);
  const float4 G2 = *(const float4*)(g2 + c), B2 = *(const float4*)(b2 + c);
  float4 o;
  o.x = (y[0] - mu2) * rinv2 * G2.x + B2.x;
  o.y = (y[1] - mu2) * rinv2 * G2.y + B2.y;
  o.z = (y[2] - mu2) * rinv2 * G2.z + B2.z;
  o.w = (y[3] - mu2) * rinv2 * G2.w + B2.w;
  *(float4*)(out + base) = o;
}

extern "C" void kernel_launch(void* const* d_in, const int* in_sizes, int n_in,
                              void* d_out, int out_size, void* d_ws, size_t ws_size,
                              hipStream_t stream) {
  const float* modal1 = (const float*)d_in[0];
  const float* modal2 = (const float*)d_in[1];
  const int*   m1     = (const int*)d_in[2];
  const int*   m2     = (const int*)d_in[3];
  const float* Wq     = (const float*)d_in[4];
  const float* bq     = (const float*)d_in[5];
  const float* Wkv    = (const float*)d_in[6];
  const float* bkv    = (const float*)d_in[7];
  const float* g1     = (const float*)d_in[8];
  const float* b1     = (const float*)d_in[9];
  // d_in[10..13] = FFN weights -> output discarded by the reference; skipped.
  const float* g2     = (const float*)d_in[14];
  const float* b2     = (const float*)d_in[15];
  float* out = (float*)d_out;

  char* ws = (char*)d_ws;
  unsigned short* q_bf  = (unsigned short*)(ws);                 //  8 MB
  unsigned short* k_bf  = (unsigned short*)(ws + 8388608);       //  8 MB
  unsigned short* kt_bf = (unsigned short*)(ws + 16777216);      //  8 MB
  unsigned short* wqt   = (unsigned short*)(ws + 25165824);      // 512 KB
  unsigned short* wkt   = (unsigned short*)(ws + 25690112);      // 512 KB
  float*          attn  = (float*)(ws + 26214400);               // 16 MB

  dim3 tb(32, 8);
  wtrans<<<dim3(16, 16, 2), tb, 0, stream>>>(Wq, Wkv, wqt, wkt);
  proj_gemm<<<dim3(64, 4, 2), 256, 0, stream>>>(modal1, modal2, wqt, wkt,
                                                bq, bkv, q_bf, k_bf, kt_bf);
  flash_attn<<<dim3(16, 32), 256, 0, stream>>>(q_bf, k_bf, kt_bf, m1, m2, attn);
  ln_fused<<<dim3(8192), 128, 0, stream>>>(attn, modal1, g1, b1, g2, b2, out);
}